// Round 2
// baseline (379.558 us; speedup 1.0000x reference)
//
#include <hip/hip_runtime.h>

#define BATCH 2
#define S_LEN 2048
#define NH 12
#define DMODEL 768
// DK = 64, scale = 1/8

typedef __attribute__((ext_vector_type(8))) short bf16x8;
typedef __attribute__((ext_vector_type(4))) float f32x4;
typedef __attribute__((ext_vector_type(4))) unsigned short us4;

__device__ __forceinline__ unsigned short f2bf(float f) {
  union { float f; unsigned int u; } v; v.f = f;
  unsigned int r = v.u + 0x7fffu + ((v.u >> 16) & 1u);  // RNE
  return (unsigned short)(r >> 16);
}

// ---------------- f32 -> bf16 convert (8 elems/thread) ----------------
__global__ void cvt_kernel(const float* __restrict__ src,
                           unsigned short* __restrict__ dst, int n8) {
  int i = blockIdx.x * blockDim.x + threadIdx.x;
  if (i >= n8) return;
  const float4* s = (const float4*)src;
  float4 a = s[i * 2], b = s[i * 2 + 1];
  us4 o0 = { f2bf(a.x), f2bf(a.y), f2bf(a.z), f2bf(a.w) };
  us4 o1 = { f2bf(b.x), f2bf(b.y), f2bf(b.z), f2bf(b.w) };
  us4* d = (us4*)dst;
  d[i * 2] = o0;
  d[i * 2 + 1] = o1;
}

#define GLD_LDS16(g, l)                                                    \
  __builtin_amdgcn_global_load_lds(                                        \
      (const __attribute__((address_space(1))) unsigned int*)(g),          \
      (__attribute__((address_space(3))) unsigned int*)(l), 16, 0, 0)

// ---------------- GEMM: C = A(M,K) @ B(N,K)^T, bf16 in, MFMA ----------
// MODE 0: bf16 row-major out, scaled.  MODE 1: bf16 V^T (B,H,64,S) out.
// MODE 2: f32 row-major out.
// Tile 128x64, BK=64, 256 threads (4 waves in 2x2), 16x16x32 bf16 MFMA.
template <int MODE>
__global__ __launch_bounds__(256, 2)
void gemm_bt(const unsigned short* __restrict__ A,
             const unsigned short* __restrict__ Bw,
             void* __restrict__ outp, int M, int N, int K, float scale) {
  __shared__ unsigned short As[128 * 64];
  __shared__ unsigned short Bs[64 * 64];
  const int m0 = blockIdx.x * 128, n0 = blockIdx.y * 64;
  const int tid = threadIdx.x, w = tid >> 6, l = tid & 63;
  const int lg = l >> 4, ll = l & 15;
  const int wm = w >> 1, wn = w & 1;
  const int lr = l >> 3, lc = (l & 7) * 8;

  f32x4 acc[4][2];
#pragma unroll
  for (int i = 0; i < 4; ++i)
#pragma unroll
    for (int j = 0; j < 2; ++j) acc[i][j] = (f32x4){0.f, 0.f, 0.f, 0.f};

  for (int k0 = 0; k0 < K; k0 += 64) {
#pragma unroll
    for (int i = 0; i < 4; ++i) {
      const unsigned short* src = A + (size_t)(m0 + w * 32 + i * 8 + lr) * K + k0 + lc;
      GLD_LDS16(src, &As[(w * 32 + i * 8) * 64]);
    }
#pragma unroll
    for (int i = 0; i < 2; ++i) {
      const unsigned short* src = Bw + (size_t)(n0 + w * 16 + i * 8 + lr) * K + k0 + lc;
      GLD_LDS16(src, &Bs[(w * 16 + i * 8) * 64]);
    }
    __syncthreads();
#pragma unroll
    for (int t = 0; t < 2; ++t) {
      bf16x8 af[4], bf[2];
#pragma unroll
      for (int mi = 0; mi < 4; ++mi)
        af[mi] = *(const bf16x8*)&As[(wm * 64 + mi * 16 + ll) * 64 + t * 32 + lg * 8];
#pragma unroll
      for (int ni = 0; ni < 2; ++ni)
        bf[ni] = *(const bf16x8*)&Bs[(wn * 32 + ni * 16 + ll) * 64 + t * 32 + lg * 8];
#pragma unroll
      for (int mi = 0; mi < 4; ++mi)
#pragma unroll
        for (int ni = 0; ni < 2; ++ni)
          acc[mi][ni] = __builtin_amdgcn_mfma_f32_16x16x32_bf16(
              af[mi], bf[ni], acc[mi][ni], 0, 0, 0);
    }
    __syncthreads();
  }

  // epilogue: C layout col = lane&15, row = (lane>>4)*4 + reg  [m89]
  if (MODE == 0) {
    unsigned short* o = (unsigned short*)outp;
#pragma unroll
    for (int mi = 0; mi < 4; ++mi)
#pragma unroll
      for (int ni = 0; ni < 2; ++ni) {
        const int col = n0 + wn * 32 + ni * 16 + ll;
        const int rowb = m0 + wm * 64 + mi * 16 + lg * 4;
#pragma unroll
        for (int r = 0; r < 4; ++r)
          o[(size_t)(rowb + r) * N + col] = f2bf(acc[mi][ni][r] * scale);
      }
  } else if (MODE == 1) {
    // V^T: feature col -> (h = col>>6, d = col&63); row -> (b, s)
    unsigned short* o = (unsigned short*)outp;
#pragma unroll
    for (int mi = 0; mi < 4; ++mi)
#pragma unroll
      for (int ni = 0; ni < 2; ++ni) {
        const int col = n0 + wn * 32 + ni * 16 + ll;
        const int row = m0 + wm * 64 + mi * 16 + lg * 4;
        const int bb = row >> 11, sidx = row & (S_LEN - 1);
        const size_t base =
            ((size_t)(bb * NH + (col >> 6)) * 64 + (col & 63)) * S_LEN + sidx;
        us4 pk = { f2bf(acc[mi][ni][0]), f2bf(acc[mi][ni][1]),
                   f2bf(acc[mi][ni][2]), f2bf(acc[mi][ni][3]) };
        *(us4*)&o[base] = pk;
      }
  } else {
    float* o = (float*)outp;
#pragma unroll
    for (int mi = 0; mi < 4; ++mi)
#pragma unroll
      for (int ni = 0; ni < 2; ++ni) {
        const int col = n0 + wn * 32 + ni * 16 + ll;
        const int rowb = m0 + wm * 64 + mi * 16 + lg * 4;
#pragma unroll
        for (int r = 0; r < 4; ++r)
          o[(size_t)(rowb + r) * N + col] = acc[mi][ni][r] * scale;
      }
  }
}

// ---------------- fused causal attention ----------------
// One WG per (q-tile pair, h, b). 4 waves; wave w owns rows qt*64+w*16..+16.
// Pass 1: online (m,l). Pass 2: recompute scores, write P f32 to d_out,
// LDS round-trip (XOR swizzle) -> bf16 A-frags, PV accumulate.
__global__ __launch_bounds__(256, 2)
void attn_fused(const unsigned short* __restrict__ Qp,
                const unsigned short* __restrict__ Kp,
                const unsigned short* __restrict__ VTp,
                float* __restrict__ attnw,
                unsigned short* __restrict__ ctx) {
  const int pairid = blockIdx.x, h = blockIdx.y, b = blockIdx.z;
  const int tid = threadIdx.x, w = tid >> 6, l = tid & 63;
  const int lg = l >> 4, ll = l & 15;
  __shared__ unsigned short plds[4][1024];  // 16x64 bf16 per wave
  char* plb = (char*)&plds[w][0];

  const unsigned short* kb = Kp + (size_t)b * S_LEN * DMODEL + h * 64;
  const unsigned short* vb = VTp + ((size_t)(b * NH + h)) * 64 * S_LEN;
  float* pbase = attnw + ((size_t)(b * NH + h)) * S_LEN * S_LEN;

  for (int half = 0; half < 2; ++half) {
    const int qt = (half == 0) ? pairid : 31 - pairid;  // balanced pairs
    const int q0 = qt * 64 + w * 16;
    const int nkt = qt + 1;

    bf16x8 qf[2];
    {
      const unsigned short* qb =
          Qp + (size_t)(b * S_LEN + q0 + ll) * DMODEL + h * 64 + lg * 8;
      qf[0] = *(const bf16x8*)qb;
      qf[1] = *(const bf16x8*)(qb + 32);
    }
    int rowg[4];
#pragma unroll
    for (int r = 0; r < 4; ++r) rowg[r] = q0 + lg * 4 + r;

    float m[4], lsum[4];
#pragma unroll
    for (int r = 0; r < 4; ++r) { m[r] = -1e30f; lsum[r] = 0.f; }

    // ---- pass 1: per-row max & sum (online) ----
    for (int kt = 0; kt < nkt; ++kt) {
      f32x4 s[4];
#pragma unroll
      for (int nb = 0; nb < 4; ++nb) s[nb] = (f32x4){0.f, 0.f, 0.f, 0.f};
#pragma unroll
      for (int t = 0; t < 2; ++t)
#pragma unroll
        for (int nb = 0; nb < 4; ++nb) {
          bf16x8 kf = *(const bf16x8*)(kb + (size_t)(kt * 64 + nb * 16 + ll) * DMODEL +
                                       t * 32 + lg * 8);
          s[nb] = __builtin_amdgcn_mfma_f32_16x16x32_bf16(qf[t], kf, s[nb], 0, 0, 0);
        }
      if (kt == nkt - 1) {  // diagonal tile: causal mask
#pragma unroll
        for (int nb = 0; nb < 4; ++nb) {
          const int col = kt * 64 + nb * 16 + ll;
#pragma unroll
          for (int r = 0; r < 4; ++r)
            if (col > rowg[r]) s[nb][r] = -1e30f;
        }
      }
      float tm[4], te[4], mn[4];
#pragma unroll
      for (int r = 0; r < 4; ++r)
        tm[r] = fmaxf(fmaxf(s[0][r], s[1][r]), fmaxf(s[2][r], s[3][r]));
#pragma unroll
      for (int off = 1; off < 16; off <<= 1)
#pragma unroll
        for (int r = 0; r < 4; ++r) tm[r] = fmaxf(tm[r], __shfl_xor(tm[r], off, 64));
#pragma unroll
      for (int r = 0; r < 4; ++r) {
        mn[r] = fmaxf(m[r], tm[r]);
        te[r] = __expf(s[0][r] - mn[r]) + __expf(s[1][r] - mn[r]) +
                __expf(s[2][r] - mn[r]) + __expf(s[3][r] - mn[r]);
      }
#pragma unroll
      for (int off = 1; off < 16; off <<= 1)
#pragma unroll
        for (int r = 0; r < 4; ++r) te[r] += __shfl_xor(te[r], off, 64);
#pragma unroll
      for (int r = 0; r < 4; ++r) {
        lsum[r] = lsum[r] * __expf(m[r] - mn[r]) + te[r];
        m[r] = mn[r];
      }
    }

    float linv[4];
#pragma unroll
    for (int r = 0; r < 4; ++r) linv[r] = 1.f / lsum[r];

    f32x4 cacc[4];
#pragma unroll
    for (int nb = 0; nb < 4; ++nb) cacc[nb] = (f32x4){0.f, 0.f, 0.f, 0.f};

    // ---- pass 2: recompute, write P, PV ----
    for (int kt = 0; kt < nkt; ++kt) {
      f32x4 s[4];
#pragma unroll
      for (int nb = 0; nb < 4; ++nb) s[nb] = (f32x4){0.f, 0.f, 0.f, 0.f};
#pragma unroll
      for (int t = 0; t < 2; ++t)
#pragma unroll
        for (int nb = 0; nb < 4; ++nb) {
          bf16x8 kf = *(const bf16x8*)(kb + (size_t)(kt * 64 + nb * 16 + ll) * DMODEL +
                                       t * 32 + lg * 8);
          s[nb] = __builtin_amdgcn_mfma_f32_16x16x32_bf16(qf[t], kf, s[nb], 0, 0, 0);
        }
#pragma unroll
      for (int nb = 0; nb < 4; ++nb) {
        const int col = kt * 64 + nb * 16 + ll;
#pragma unroll
        for (int r = 0; r < 4; ++r) {
          float p = (col <= rowg[r]) ? __expf(s[nb][r] - m[r]) * linv[r] : 0.f;
          pbase[(size_t)rowg[r] * S_LEN + col] = p;
          const int rl = lg * 4 + r;
          const int bo = ((rl * 64 + nb * 16 + ll) * 2) ^ ((rl & 7) << 4);
          *(unsigned short*)(plb + bo) = f2bf(p);
        }
      }
      __syncthreads();  // P tile visible (RAW)
      bf16x8 pf[2];
#pragma unroll
      for (int t = 0; t < 2; ++t) {
        const int bo = ((ll * 64 + t * 32 + lg * 8) * 2) ^ ((ll & 7) << 4);
        pf[t] = *(const bf16x8*)(plb + bo);
      }
#pragma unroll
      for (int t = 0; t < 2; ++t)
#pragma unroll
        for (int nb = 0; nb < 4; ++nb) {
          bf16x8 vf = *(const bf16x8*)(vb + (size_t)(nb * 16 + ll) * S_LEN +
                                       kt * 64 + t * 32 + lg * 8);
          cacc[nb] = __builtin_amdgcn_mfma_f32_16x16x32_bf16(pf[t], vf, cacc[nb], 0, 0, 0);
        }
      __syncthreads();  // WAR before next tile's writes
    }

    // ---- zero-fill masked columns (must overwrite 0xAA poison) ----
    const int zc = nkt * 64;
    for (int rr = 0; rr < 16; ++rr) {
      float* dst = pbase + (size_t)(qt * 64 + w * 16 + rr) * S_LEN;
      for (int c = zc + l * 4; c < S_LEN; c += 256)
        *(float4*)(dst + c) = make_float4(0.f, 0.f, 0.f, 0.f);
    }

    // ---- context write (bf16, (B,S,D) layout) ----
#pragma unroll
    for (int nb = 0; nb < 4; ++nb)
#pragma unroll
      for (int r = 0; r < 4; ++r)
        ctx[(size_t)(b * S_LEN + rowg[r]) * DMODEL + h * 64 + nb * 16 + ll] =
            f2bf(cacc[nb][r]);
  }
}

extern "C" void kernel_launch(void* const* d_in, const int* in_sizes, int n_in,
                              void* d_out, int out_size, void* d_ws, size_t ws_size,
                              hipStream_t stream) {
  const float* q_in = (const float*)d_in[0];
  const float* k_in = (const float*)d_in[1];
  const float* v_in = (const float*)d_in[2];
  // d_in[3] = mask: causal triu(k=1), hardcoded in attn kernel
  const float* wq = (const float*)d_in[4];
  const float* wk = (const float*)d_in[5];
  const float* wv = (const float*)d_in[6];
  const float* wo = (const float*)d_in[7];

  const int BSD = BATCH * S_LEN * DMODEL;  // 3145728
  const int DD = DMODEL * DMODEL;          // 589824
  const int M = BATCH * S_LEN;             // 4096

  char* ws = (char*)d_ws;
  unsigned short* qbf = (unsigned short*)ws;  ws += (size_t)BSD * 2;
  unsigned short* kbf = (unsigned short*)ws;  ws += (size_t)BSD * 2;
  unsigned short* vbf = (unsigned short*)ws;  ws += (size_t)BSD * 2;
  unsigned short* wqb = (unsigned short*)ws;  ws += (size_t)DD * 2;
  unsigned short* wkb = (unsigned short*)ws;  ws += (size_t)DD * 2;
  unsigned short* wvb = (unsigned short*)ws;  ws += (size_t)DD * 2;
  unsigned short* wob = (unsigned short*)ws;  ws += (size_t)DD * 2;
  unsigned short* Qs  = (unsigned short*)ws;  ws += (size_t)BSD * 2;
  unsigned short* Ks  = (unsigned short*)ws;  ws += (size_t)BSD * 2;
  unsigned short* VT  = (unsigned short*)ws;  ws += (size_t)BSD * 2;
  unsigned short* ctx = (unsigned short*)ws;  ws += (size_t)BSD * 2;

  float* out_proj = (float*)d_out;
  float* attnw = (float*)d_out + BSD;

  // f32 -> bf16
  cvt_kernel<<<BSD / 8 / 256, 256, 0, stream>>>(q_in, qbf, BSD / 8);
  cvt_kernel<<<BSD / 8 / 256, 256, 0, stream>>>(k_in, kbf, BSD / 8);
  cvt_kernel<<<BSD / 8 / 256, 256, 0, stream>>>(v_in, vbf, BSD / 8);
  cvt_kernel<<<DD / 8 / 256, 256, 0, stream>>>(wq, wqb, DD / 8);
  cvt_kernel<<<DD / 8 / 256, 256, 0, stream>>>(wk, wkb, DD / 8);
  cvt_kernel<<<DD / 8 / 256, 256, 0, stream>>>(wv, wvb, DD / 8);
  cvt_kernel<<<DD / 8 / 256, 256, 0, stream>>>(wo, wob, DD / 8);

  dim3 ggrid(M / 128, DMODEL / 64);  // 32 x 12
  // Q scaled by 1/sqrt(DK)=1/8 (exact pow2, folded into Q)
  gemm_bt<0><<<ggrid, 256, 0, stream>>>(qbf, wqb, Qs, M, DMODEL, DMODEL, 0.125f);
  gemm_bt<0><<<ggrid, 256, 0, stream>>>(kbf, wkb, Ks, M, DMODEL, DMODEL, 1.0f);
  gemm_bt<1><<<ggrid, 256, 0, stream>>>(vbf, wvb, VT, M, DMODEL, DMODEL, 1.0f);

  attn_fused<<<dim3(16, NH, BATCH), 256, 0, stream>>>(Qs, Ks, VT, attnw, ctx);

  gemm_bt<2><<<ggrid, 256, 0, stream>>>(ctx, wob, out_proj, M, DMODEL, DMODEL, 1.0f);
}

// Round 3
// 304.097 us; speedup vs baseline: 1.2481x; 1.2481x over previous
//
#include <hip/hip_runtime.h>

#define BATCH 2
#define S_LEN 2048
#define NH 12
#define DMODEL 768
// DK = 64, scale = 1/8

typedef __attribute__((ext_vector_type(8))) short bf16x8;
typedef __attribute__((ext_vector_type(4))) float f32x4;
typedef __attribute__((ext_vector_type(4))) unsigned short us4;

__device__ __forceinline__ unsigned short f2bf(float f) {
  union { float f; unsigned int u; } v; v.f = f;
  unsigned int r = v.u + 0x7fffu + ((v.u >> 16) & 1u);  // RNE
  return (unsigned short)(r >> 16);
}

// ---------------- f32 -> bf16 convert (8 elems/thread) ----------------
__global__ void cvt_kernel(const float* __restrict__ src,
                           unsigned short* __restrict__ dst, int n8) {
  int i = blockIdx.x * blockDim.x + threadIdx.x;
  if (i >= n8) return;
  const float4* s = (const float4*)src;
  float4 a = s[i * 2], b = s[i * 2 + 1];
  us4 o0 = { f2bf(a.x), f2bf(a.y), f2bf(a.z), f2bf(a.w) };
  us4 o1 = { f2bf(b.x), f2bf(b.y), f2bf(b.z), f2bf(b.w) };
  us4* d = (us4*)dst;
  d[i * 2] = o0;
  d[i * 2 + 1] = o1;
}

#define GLD_LDS16(g, l)                                                    \
  __builtin_amdgcn_global_load_lds(                                        \
      (const __attribute__((address_space(1))) unsigned int*)(g),          \
      (__attribute__((address_space(3))) unsigned int*)(l), 16, 0, 0)

// ---------------- GEMM: C = A(M,K) @ B(N,K)^T, bf16 in, MFMA ----------
// MODE 0: bf16 row-major out, scaled.  MODE 1: bf16 V^T (B,H,64,S) out.
// MODE 2: f32 row-major out.
// Tile 128x64, BK=64, 256 threads (4 waves in 2x2), 16x16x32 bf16 MFMA.
template <int MODE>
__global__ __launch_bounds__(256, 2)
void gemm_bt(const unsigned short* __restrict__ A,
             const unsigned short* __restrict__ Bw,
             void* __restrict__ outp, int M, int N, int K, float scale) {
  __shared__ unsigned short As[128 * 64];
  __shared__ unsigned short Bs[64 * 64];
  const int m0 = blockIdx.x * 128, n0 = blockIdx.y * 64;
  const int tid = threadIdx.x, w = tid >> 6, l = tid & 63;
  const int lg = l >> 4, ll = l & 15;
  const int wm = w >> 1, wn = w & 1;
  const int lr = l >> 3, lc = (l & 7) * 8;

  f32x4 acc[4][2];
#pragma unroll
  for (int i = 0; i < 4; ++i)
#pragma unroll
    for (int j = 0; j < 2; ++j) acc[i][j] = (f32x4){0.f, 0.f, 0.f, 0.f};

  for (int k0 = 0; k0 < K; k0 += 64) {
#pragma unroll
    for (int i = 0; i < 4; ++i) {
      const unsigned short* src = A + (size_t)(m0 + w * 32 + i * 8 + lr) * K + k0 + lc;
      GLD_LDS16(src, &As[(w * 32 + i * 8) * 64]);
    }
#pragma unroll
    for (int i = 0; i < 2; ++i) {
      const unsigned short* src = Bw + (size_t)(n0 + w * 16 + i * 8 + lr) * K + k0 + lc;
      GLD_LDS16(src, &Bs[(w * 16 + i * 8) * 64]);
    }
    __syncthreads();
#pragma unroll
    for (int t = 0; t < 2; ++t) {
      bf16x8 af[4], bf[2];
#pragma unroll
      for (int mi = 0; mi < 4; ++mi)
        af[mi] = *(const bf16x8*)&As[(wm * 64 + mi * 16 + ll) * 64 + t * 32 + lg * 8];
#pragma unroll
      for (int ni = 0; ni < 2; ++ni)
        bf[ni] = *(const bf16x8*)&Bs[(wn * 32 + ni * 16 + ll) * 64 + t * 32 + lg * 8];
#pragma unroll
      for (int mi = 0; mi < 4; ++mi)
#pragma unroll
        for (int ni = 0; ni < 2; ++ni)
          acc[mi][ni] = __builtin_amdgcn_mfma_f32_16x16x32_bf16(
              af[mi], bf[ni], acc[mi][ni], 0, 0, 0);
    }
    __syncthreads();
  }

  // epilogue: C layout col = lane&15, row = (lane>>4)*4 + reg  [m89]
  if (MODE == 0) {
    unsigned short* o = (unsigned short*)outp;
#pragma unroll
    for (int mi = 0; mi < 4; ++mi)
#pragma unroll
      for (int ni = 0; ni < 2; ++ni) {
        const int col = n0 + wn * 32 + ni * 16 + ll;
        const int rowb = m0 + wm * 64 + mi * 16 + lg * 4;
#pragma unroll
        for (int r = 0; r < 4; ++r)
          o[(size_t)(rowb + r) * N + col] = f2bf(acc[mi][ni][r] * scale);
      }
  } else if (MODE == 1) {
    // V^T: feature col -> (h = col>>6, d = col&63); row -> (b, s)
    unsigned short* o = (unsigned short*)outp;
#pragma unroll
    for (int mi = 0; mi < 4; ++mi)
#pragma unroll
      for (int ni = 0; ni < 2; ++ni) {
        const int col = n0 + wn * 32 + ni * 16 + ll;
        const int row = m0 + wm * 64 + mi * 16 + lg * 4;
        const int bb = row >> 11, sidx = row & (S_LEN - 1);
        const size_t base =
            ((size_t)(bb * NH + (col >> 6)) * 64 + (col & 63)) * S_LEN + sidx;
        us4 pk = { f2bf(acc[mi][ni][0]), f2bf(acc[mi][ni][1]),
                   f2bf(acc[mi][ni][2]), f2bf(acc[mi][ni][3]) };
        *(us4*)&o[base] = pk;
      }
  } else {
    float* o = (float*)outp;
#pragma unroll
    for (int mi = 0; mi < 4; ++mi)
#pragma unroll
      for (int ni = 0; ni < 2; ++ni) {
        const int col = n0 + wn * 32 + ni * 16 + ll;
        const int rowb = m0 + wm * 64 + mi * 16 + lg * 4;
#pragma unroll
        for (int r = 0; r < 4; ++r)
          o[(size_t)(rowb + r) * N + col] = acc[mi][ni][r] * scale;
      }
  }
}

// ---------------- fused causal attention ----------------
// One WG per (q-tile, h, b), flattened 1-D grid, heaviest q-tiles first.
// 4 waves; wave w owns rows qt*64+w*16..+16.
// Pass 1: per-lane online (m,l), ONE butterfly combine at the end.
// Pass 2: recompute scores, write P f32 to d_out, per-wave LDS round-trip
// (XOR swizzle, NO barriers - LDS tile is wave-private) -> bf16 A-frags, PV.
__global__ __launch_bounds__(256, 2)
void attn_fused(const unsigned short* __restrict__ Qp,
                const unsigned short* __restrict__ Kp,
                const unsigned short* __restrict__ VTp,
                float* __restrict__ attnw,
                unsigned short* __restrict__ ctx) {
  const int idx = blockIdx.x;
  const int qt = 31 - idx / (NH * BATCH);  // heavy tiles launch first
  const int hb = idx % (NH * BATCH);
  const int h = hb >> 1, b = hb & 1;
  const int tid = threadIdx.x, w = tid >> 6, l = tid & 63;
  const int lg = l >> 4, ll = l & 15;
  __shared__ unsigned short plds[4][1024];  // 16x64 bf16 per wave (private)
  char* plb = (char*)&plds[w][0];

  const unsigned short* kb = Kp + (size_t)b * S_LEN * DMODEL + h * 64;
  const unsigned short* vb = VTp + ((size_t)(b * NH + h)) * 64 * S_LEN;
  float* pbase = attnw + ((size_t)(b * NH + h)) * S_LEN * S_LEN;

  const int q0 = qt * 64 + w * 16;
  const int nkt = qt + 1;

  bf16x8 qf[2];
  {
    const unsigned short* qb =
        Qp + (size_t)(b * S_LEN + q0 + ll) * DMODEL + h * 64 + lg * 8;
    qf[0] = *(const bf16x8*)qb;
    qf[1] = *(const bf16x8*)(qb + 32);
  }
  int rowg[4];
#pragma unroll
  for (int r = 0; r < 4; ++r) rowg[r] = q0 + lg * 4 + r;

  float m[4], lsum[4];
#pragma unroll
  for (int r = 0; r < 4; ++r) { m[r] = -1e30f; lsum[r] = 0.f; }

  // ---- pass 1: per-lane online (m,l); no cross-lane ops in the loop ----
  for (int kt = 0; kt < nkt; ++kt) {
    f32x4 s[4];
#pragma unroll
    for (int nb = 0; nb < 4; ++nb) s[nb] = (f32x4){0.f, 0.f, 0.f, 0.f};
#pragma unroll
    for (int t = 0; t < 2; ++t)
#pragma unroll
      for (int nb = 0; nb < 4; ++nb) {
        bf16x8 kf = *(const bf16x8*)(kb + (size_t)(kt * 64 + nb * 16 + ll) * DMODEL +
                                     t * 32 + lg * 8);
        s[nb] = __builtin_amdgcn_mfma_f32_16x16x32_bf16(qf[t], kf, s[nb], 0, 0, 0);
      }
    if (kt == nkt - 1) {  // diagonal tile: causal mask
#pragma unroll
      for (int nb = 0; nb < 4; ++nb) {
        const int col = kt * 64 + nb * 16 + ll;
#pragma unroll
        for (int r = 0; r < 4; ++r)
          if (col > rowg[r]) s[nb][r] = -1e30f;
      }
    }
#pragma unroll
    for (int r = 0; r < 4; ++r) {
      float tm = fmaxf(fmaxf(s[0][r], s[1][r]), fmaxf(s[2][r], s[3][r]));
      float mn = fmaxf(m[r], tm);
      float te = __expf(s[0][r] - mn) + __expf(s[1][r] - mn) +
                 __expf(s[2][r] - mn) + __expf(s[3][r] - mn);
      lsum[r] = lsum[r] * __expf(m[r] - mn) + te;
      m[r] = mn;
    }
  }
  // ---- one butterfly combine over the 16 lanes sharing rows ----
#pragma unroll
  for (int off = 1; off < 16; off <<= 1)
#pragma unroll
    for (int r = 0; r < 4; ++r) {
      float om = __shfl_xor(m[r], off, 64);
      float ol = __shfl_xor(lsum[r], off, 64);
      float mn = fmaxf(m[r], om);
      lsum[r] = lsum[r] * __expf(m[r] - mn) + ol * __expf(om - mn);
      m[r] = mn;
    }

  float linv[4];
#pragma unroll
  for (int r = 0; r < 4; ++r) linv[r] = 1.f / lsum[r];

  f32x4 cacc[4];
#pragma unroll
  for (int nb = 0; nb < 4; ++nb) cacc[nb] = (f32x4){0.f, 0.f, 0.f, 0.f};

  // ---- pass 2: recompute, write P, PV (wave-private LDS, no barriers) ----
  for (int kt = 0; kt < nkt; ++kt) {
    f32x4 s[4];
#pragma unroll
    for (int nb = 0; nb < 4; ++nb) s[nb] = (f32x4){0.f, 0.f, 0.f, 0.f};
#pragma unroll
    for (int t = 0; t < 2; ++t)
#pragma unroll
      for (int nb = 0; nb < 4; ++nb) {
        bf16x8 kf = *(const bf16x8*)(kb + (size_t)(kt * 64 + nb * 16 + ll) * DMODEL +
                                     t * 32 + lg * 8);
        s[nb] = __builtin_amdgcn_mfma_f32_16x16x32_bf16(qf[t], kf, s[nb], 0, 0, 0);
      }
#pragma unroll
    for (int nb = 0; nb < 4; ++nb) {
      const int col = kt * 64 + nb * 16 + ll;
#pragma unroll
      for (int r = 0; r < 4; ++r) {
        float p = (col <= rowg[r]) ? __expf(s[nb][r] - m[r]) * linv[r] : 0.f;
        pbase[(size_t)rowg[r] * S_LEN + col] = p;
        const int rl = lg * 4 + r;
        const int bo = ((rl * 64 + nb * 16 + ll) * 2) ^ ((rl & 7) << 4);
        *(unsigned short*)(plb + bo) = f2bf(p);
      }
    }
    // wave-private LDS: compiler-inserted lgkmcnt orders write->read
    bf16x8 pf[2];
#pragma unroll
    for (int t = 0; t < 2; ++t) {
      const int bo = ((ll * 64 + t * 32 + lg * 8) * 2) ^ ((ll & 7) << 4);
      pf[t] = *(const bf16x8*)(plb + bo);
    }
#pragma unroll
    for (int t = 0; t < 2; ++t)
#pragma unroll
      for (int nb = 0; nb < 4; ++nb) {
        bf16x8 vf = *(const bf16x8*)(vb + (size_t)(nb * 16 + ll) * S_LEN +
                                     kt * 64 + t * 32 + lg * 8);
        cacc[nb] = __builtin_amdgcn_mfma_f32_16x16x32_bf16(pf[t], vf, cacc[nb], 0, 0, 0);
      }
  }

  // ---- zero-fill masked columns (must overwrite 0xAA poison) ----
  const int zc = nkt * 64;
  for (int rr = 0; rr < 16; ++rr) {
    float* dst = pbase + (size_t)(q0 + rr) * S_LEN;
    for (int c = zc + l * 4; c < S_LEN; c += 256)
      *(float4*)(dst + c) = make_float4(0.f, 0.f, 0.f, 0.f);
  }

  // ---- context write (bf16, (B,S,D) layout) ----
#pragma unroll
  for (int nb = 0; nb < 4; ++nb)
#pragma unroll
    for (int r = 0; r < 4; ++r)
      ctx[(size_t)(b * S_LEN + rowg[r]) * DMODEL + h * 64 + nb * 16 + ll] =
          f2bf(cacc[nb][r]);
}

extern "C" void kernel_launch(void* const* d_in, const int* in_sizes, int n_in,
                              void* d_out, int out_size, void* d_ws, size_t ws_size,
                              hipStream_t stream) {
  const float* q_in = (const float*)d_in[0];
  const float* k_in = (const float*)d_in[1];
  const float* v_in = (const float*)d_in[2];
  // d_in[3] = mask: causal triu(k=1), hardcoded in attn kernel
  const float* wq = (const float*)d_in[4];
  const float* wk = (const float*)d_in[5];
  const float* wv = (const float*)d_in[6];
  const float* wo = (const float*)d_in[7];

  const int BSD = BATCH * S_LEN * DMODEL;  // 3145728
  const int DD = DMODEL * DMODEL;          // 589824
  const int M = BATCH * S_LEN;             // 4096

  char* ws = (char*)d_ws;
  unsigned short* qbf = (unsigned short*)ws;  ws += (size_t)BSD * 2;
  unsigned short* kbf = (unsigned short*)ws;  ws += (size_t)BSD * 2;
  unsigned short* vbf = (unsigned short*)ws;  ws += (size_t)BSD * 2;
  unsigned short* wqb = (unsigned short*)ws;  ws += (size_t)DD * 2;
  unsigned short* wkb = (unsigned short*)ws;  ws += (size_t)DD * 2;
  unsigned short* wvb = (unsigned short*)ws;  ws += (size_t)DD * 2;
  unsigned short* wob = (unsigned short*)ws;  ws += (size_t)DD * 2;
  unsigned short* Qs  = (unsigned short*)ws;  ws += (size_t)BSD * 2;
  unsigned short* Ks  = (unsigned short*)ws;  ws += (size_t)BSD * 2;
  unsigned short* VT  = (unsigned short*)ws;  ws += (size_t)BSD * 2;
  unsigned short* ctx = (unsigned short*)ws;  ws += (size_t)BSD * 2;

  float* out_proj = (float*)d_out;
  float* attnw = (float*)d_out + BSD;

  // f32 -> bf16
  cvt_kernel<<<BSD / 8 / 256, 256, 0, stream>>>(q_in, qbf, BSD / 8);
  cvt_kernel<<<BSD / 8 / 256, 256, 0, stream>>>(k_in, kbf, BSD / 8);
  cvt_kernel<<<BSD / 8 / 256, 256, 0, stream>>>(v_in, vbf, BSD / 8);
  cvt_kernel<<<DD / 8 / 256, 256, 0, stream>>>(wq, wqb, DD / 8);
  cvt_kernel<<<DD / 8 / 256, 256, 0, stream>>>(wk, wkb, DD / 8);
  cvt_kernel<<<DD / 8 / 256, 256, 0, stream>>>(wv, wvb, DD / 8);
  cvt_kernel<<<DD / 8 / 256, 256, 0, stream>>>(wo, wob, DD / 8);

  dim3 ggrid(M / 128, DMODEL / 64);  // 32 x 12
  // Q scaled by 1/sqrt(DK)=1/8 (exact pow2, folded into Q)
  gemm_bt<0><<<ggrid, 256, 0, stream>>>(qbf, wqb, Qs, M, DMODEL, DMODEL, 0.125f);
  gemm_bt<0><<<ggrid, 256, 0, stream>>>(kbf, wkb, Ks, M, DMODEL, DMODEL, 1.0f);
  gemm_bt<1><<<ggrid, 256, 0, stream>>>(vbf, wvb, VT, M, DMODEL, DMODEL, 1.0f);

  attn_fused<<<32 * NH * BATCH, 256, 0, stream>>>(Qs, Ks, VT, attnw, ctx);

  gemm_bt<2><<<ggrid, 256, 0, stream>>>(ctx, wob, out_proj, M, DMODEL, DMODEL, 1.0f);
}

// Round 4
// 282.919 us; speedup vs baseline: 1.3416x; 1.0749x over previous
//
#include <hip/hip_runtime.h>

#define BATCH 2
#define S_LEN 2048
#define NH 12
#define DMODEL 768
// DK = 64, scale = 1/8

#define N8_BSD (BATCH * S_LEN * DMODEL / 8)  // 393216
#define N8_DD (DMODEL * DMODEL / 8)          // 73728

typedef __attribute__((ext_vector_type(8))) short bf16x8;
typedef __attribute__((ext_vector_type(4))) float f32x4;
typedef __attribute__((ext_vector_type(4))) unsigned short us4;

__device__ __forceinline__ unsigned short f2bf(float f) {
  union { float f; unsigned int u; } v; v.f = f;
  unsigned int r = v.u + 0x7fffu + ((v.u >> 16) & 1u);  // RNE
  return (unsigned short)(r >> 16);
}

// ---------------- f32 -> bf16 converts (8 elems/thread) ----------------
__global__ void cvt3_kernel(const float* __restrict__ s0,
                            const float* __restrict__ s1,
                            const float* __restrict__ s2,
                            unsigned short* __restrict__ dst) {
  int i = blockIdx.x * blockDim.x + threadIdx.x;  // 0 .. 3*N8_BSD-1 (exact)
  int j = i / N8_BSD;
  int k = i - j * N8_BSD;
  const float* s = (j == 0) ? s0 : (j == 1) ? s1 : s2;
  const float4* sp = (const float4*)s;
  float4 a = sp[k * 2], b = sp[k * 2 + 1];
  us4 o0 = { f2bf(a.x), f2bf(a.y), f2bf(a.z), f2bf(a.w) };
  us4 o1 = { f2bf(b.x), f2bf(b.y), f2bf(b.z), f2bf(b.w) };
  us4* d = (us4*)dst;
  d[i * 2] = o0;
  d[i * 2 + 1] = o1;
}

__global__ void cvt4_kernel(const float* __restrict__ s0,
                            const float* __restrict__ s1,
                            const float* __restrict__ s2,
                            const float* __restrict__ s3,
                            unsigned short* __restrict__ dst) {
  int i = blockIdx.x * blockDim.x + threadIdx.x;  // 0 .. 4*N8_DD-1 (exact)
  int j = i / N8_DD;
  int k = i - j * N8_DD;
  const float* s = (j == 0) ? s0 : (j == 1) ? s1 : (j == 2) ? s2 : s3;
  const float4* sp = (const float4*)s;
  float4 a = sp[k * 2], b = sp[k * 2 + 1];
  us4 o0 = { f2bf(a.x), f2bf(a.y), f2bf(a.z), f2bf(a.w) };
  us4 o1 = { f2bf(b.x), f2bf(b.y), f2bf(b.z), f2bf(b.w) };
  us4* d = (us4*)dst;
  d[i * 2] = o0;
  d[i * 2 + 1] = o1;
}

#define GLD_LDS16(g, l)                                                    \
  __builtin_amdgcn_global_load_lds(                                        \
      (const __attribute__((address_space(1))) unsigned int*)(g),          \
      (__attribute__((address_space(3))) unsigned int*)(l), 16, 0, 0)

// ---------------- fused QKV projection GEMM ----------------
// grid (32, 36): n0g = blockIdx.y*64 selects Q (0..767), K (768..1535),
// V (1536..2303). W3 = [2304][768] contiguous (wq;wk;wv). Tile 128x64, BK=64.
__global__ __launch_bounds__(256, 2)
void gemm_qkv(const unsigned short* __restrict__ Aq,
              const unsigned short* __restrict__ Ak,
              const unsigned short* __restrict__ Av,
              const unsigned short* __restrict__ W3,
              unsigned short* __restrict__ Qs,
              unsigned short* __restrict__ Ks,
              unsigned short* __restrict__ VT) {
  __shared__ unsigned short As[128 * 64];
  __shared__ unsigned short Bs[64 * 64];
  const int m0 = blockIdx.x * 128;
  const int n0g = blockIdx.y * 64;
  const int nblk = n0g / 768;         // 0=Q 1=K 2=V (uniform per block)
  const int n0 = n0g - nblk * 768;
  const unsigned short* A = (nblk == 0) ? Aq : (nblk == 1) ? Ak : Av;
  const unsigned short* Bw = W3 + (size_t)n0g * DMODEL;
  const int tid = threadIdx.x, w = tid >> 6, l = tid & 63;
  const int lg = l >> 4, ll = l & 15;
  const int wm = w >> 1, wn = w & 1;
  const int lr = l >> 3, lc = (l & 7) * 8;

  f32x4 acc[4][2];
#pragma unroll
  for (int i = 0; i < 4; ++i)
#pragma unroll
    for (int j = 0; j < 2; ++j) acc[i][j] = (f32x4){0.f, 0.f, 0.f, 0.f};

  for (int k0 = 0; k0 < DMODEL; k0 += 64) {
#pragma unroll
    for (int i = 0; i < 4; ++i) {
      const unsigned short* src =
          A + (size_t)(m0 + w * 32 + i * 8 + lr) * DMODEL + k0 + lc;
      GLD_LDS16(src, &As[(w * 32 + i * 8) * 64]);
    }
#pragma unroll
    for (int i = 0; i < 2; ++i) {
      const unsigned short* src =
          Bw + (size_t)(w * 16 + i * 8 + lr) * DMODEL + k0 + lc;
      GLD_LDS16(src, &Bs[(w * 16 + i * 8) * 64]);
    }
    __syncthreads();
#pragma unroll
    for (int t = 0; t < 2; ++t) {
      bf16x8 af[4], bf[2];
#pragma unroll
      for (int mi = 0; mi < 4; ++mi)
        af[mi] = *(const bf16x8*)&As[(wm * 64 + mi * 16 + ll) * 64 + t * 32 + lg * 8];
#pragma unroll
      for (int ni = 0; ni < 2; ++ni)
        bf[ni] = *(const bf16x8*)&Bs[(wn * 32 + ni * 16 + ll) * 64 + t * 32 + lg * 8];
#pragma unroll
      for (int mi = 0; mi < 4; ++mi)
#pragma unroll
        for (int ni = 0; ni < 2; ++ni)
          acc[mi][ni] = __builtin_amdgcn_mfma_f32_16x16x32_bf16(
              af[mi], bf[ni], acc[mi][ni], 0, 0, 0);
    }
    __syncthreads();
  }

  if (nblk < 2) {  // Q or K: row-major [4096][768]; Q scaled by 1/8
    unsigned short* o = nblk ? Ks : Qs;
    const float sc = nblk ? 1.f : 0.125f;
#pragma unroll
    for (int mi = 0; mi < 4; ++mi)
#pragma unroll
      for (int ni = 0; ni < 2; ++ni) {
        const int col = n0 + wn * 32 + ni * 16 + ll;
        const int rowb = m0 + wm * 64 + mi * 16 + lg * 4;
#pragma unroll
        for (int r = 0; r < 4; ++r)
          o[(size_t)(rowb + r) * 768 + col] = f2bf(acc[mi][ni][r] * sc);
      }
  } else {  // V^T: (B,H,64,S)
#pragma unroll
    for (int mi = 0; mi < 4; ++mi)
#pragma unroll
      for (int ni = 0; ni < 2; ++ni) {
        const int col = n0 + wn * 32 + ni * 16 + ll;
        const int row = m0 + wm * 64 + mi * 16 + lg * 4;
        const int bb = row >> 11, sidx = row & (S_LEN - 1);
        const size_t base =
            ((size_t)(bb * NH + (col >> 6)) * 64 + (col & 63)) * S_LEN + sidx;
        us4 pk = { f2bf(acc[mi][ni][0]), f2bf(acc[mi][ni][1]),
                   f2bf(acc[mi][ni][2]), f2bf(acc[mi][ni][3]) };
        *(us4*)&VT[base] = pk;
      }
  }
}

// ---------------- output projection GEMM (f32 out) ----------------
__global__ __launch_bounds__(256, 2)
void gemm_proj(const unsigned short* __restrict__ A,
               const unsigned short* __restrict__ Bw,
               float* __restrict__ o) {
  __shared__ unsigned short As[128 * 64];
  __shared__ unsigned short Bs[64 * 64];
  const int m0 = blockIdx.x * 128, n0 = blockIdx.y * 64;
  const int tid = threadIdx.x, w = tid >> 6, l = tid & 63;
  const int lg = l >> 4, ll = l & 15;
  const int wm = w >> 1, wn = w & 1;
  const int lr = l >> 3, lc = (l & 7) * 8;

  f32x4 acc[4][2];
#pragma unroll
  for (int i = 0; i < 4; ++i)
#pragma unroll
    for (int j = 0; j < 2; ++j) acc[i][j] = (f32x4){0.f, 0.f, 0.f, 0.f};

  for (int k0 = 0; k0 < DMODEL; k0 += 64) {
#pragma unroll
    for (int i = 0; i < 4; ++i) {
      const unsigned short* src =
          A + (size_t)(m0 + w * 32 + i * 8 + lr) * DMODEL + k0 + lc;
      GLD_LDS16(src, &As[(w * 32 + i * 8) * 64]);
    }
#pragma unroll
    for (int i = 0; i < 2; ++i) {
      const unsigned short* src =
          Bw + (size_t)(n0 + w * 16 + i * 8 + lr) * DMODEL + k0 + lc;
      GLD_LDS16(src, &Bs[(w * 16 + i * 8) * 64]);
    }
    __syncthreads();
#pragma unroll
    for (int t = 0; t < 2; ++t) {
      bf16x8 af[4], bf[2];
#pragma unroll
      for (int mi = 0; mi < 4; ++mi)
        af[mi] = *(const bf16x8*)&As[(wm * 64 + mi * 16 + ll) * 64 + t * 32 + lg * 8];
#pragma unroll
      for (int ni = 0; ni < 2; ++ni)
        bf[ni] = *(const bf16x8*)&Bs[(wn * 32 + ni * 16 + ll) * 64 + t * 32 + lg * 8];
#pragma unroll
      for (int mi = 0; mi < 4; ++mi)
#pragma unroll
        for (int ni = 0; ni < 2; ++ni)
          acc[mi][ni] = __builtin_amdgcn_mfma_f32_16x16x32_bf16(
              af[mi], bf[ni], acc[mi][ni], 0, 0, 0);
    }
    __syncthreads();
  }

#pragma unroll
  for (int mi = 0; mi < 4; ++mi)
#pragma unroll
    for (int ni = 0; ni < 2; ++ni) {
      const int col = n0 + wn * 32 + ni * 16 + ll;
      const int rowb = m0 + wm * 64 + mi * 16 + lg * 4;
#pragma unroll
      for (int r = 0; r < 4; ++r)
        o[(size_t)(rowb + r) * DMODEL + col] = acc[mi][ni][r];
    }
}

// ---------------- attn pass 1: online (m, 1/l) + zero-fill ----------------
// One WG per (q-tile, h, b); 4 waves; wave w owns rows qt*64+w*16..+16.
// Register double-buffered K prefetch; per-lane online (m,l); one butterfly.
__global__ __launch_bounds__(256, 3)
void attn_ml(const unsigned short* __restrict__ Qp,
             const unsigned short* __restrict__ Kp,
             float2* __restrict__ mlbuf,
             float* __restrict__ attnw) {
  const int idx = blockIdx.x;
  const int qt = 31 - idx / (NH * BATCH);  // heavy tiles first
  const int hb = idx % (NH * BATCH);
  const int h = hb >> 1, b = hb & 1;
  const int tid = threadIdx.x, w = tid >> 6, l = tid & 63;
  const int lg = l >> 4, ll = l & 15;

  const unsigned short* kbp = Kp + (size_t)b * S_LEN * DMODEL + h * 64;
  const int q0 = qt * 64 + w * 16;
  const int nkt = qt + 1;

  bf16x8 qf[2];
  {
    const unsigned short* qb =
        Qp + (size_t)(b * S_LEN + q0 + ll) * DMODEL + h * 64 + lg * 8;
    qf[0] = *(const bf16x8*)qb;
    qf[1] = *(const bf16x8*)(qb + 32);
  }
  int rowg[4];
#pragma unroll
  for (int r = 0; r < 4; ++r) rowg[r] = q0 + lg * 4 + r;

  float m[4], lsum[4];
#pragma unroll
  for (int r = 0; r < 4; ++r) { m[r] = -1e30f; lsum[r] = 0.f; }

  auto LOADK = [&](bf16x8* kf, int kt) {
#pragma unroll
    for (int t = 0; t < 2; ++t)
#pragma unroll
      for (int nb = 0; nb < 4; ++nb)
        kf[t * 4 + nb] = *(const bf16x8*)(kbp +
            (size_t)(kt * 64 + nb * 16 + ll) * DMODEL + t * 32 + lg * 8);
  };

  auto P1TILE = [&](const bf16x8* kf, int kt) {
    f32x4 s[4];
#pragma unroll
    for (int nb = 0; nb < 4; ++nb) s[nb] = (f32x4){0.f, 0.f, 0.f, 0.f};
#pragma unroll
    for (int t = 0; t < 2; ++t)
#pragma unroll
      for (int nb = 0; nb < 4; ++nb)
        s[nb] = __builtin_amdgcn_mfma_f32_16x16x32_bf16(qf[t], kf[t * 4 + nb],
                                                        s[nb], 0, 0, 0);
    if (kt == nkt - 1) {  // diagonal: causal mask
#pragma unroll
      for (int nb = 0; nb < 4; ++nb) {
        const int col = kt * 64 + nb * 16 + ll;
#pragma unroll
        for (int r = 0; r < 4; ++r)
          if (col > rowg[r]) s[nb][r] = -1e30f;
      }
    }
#pragma unroll
    for (int r = 0; r < 4; ++r) {
      float tm = fmaxf(fmaxf(s[0][r], s[1][r]), fmaxf(s[2][r], s[3][r]));
      float mn = fmaxf(m[r], tm);
      float te = __expf(s[0][r] - mn) + __expf(s[1][r] - mn) +
                 __expf(s[2][r] - mn) + __expf(s[3][r] - mn);
      lsum[r] = lsum[r] * __expf(m[r] - mn) + te;
      m[r] = mn;
    }
  };

  {
    bf16x8 ka[8], kb2[8];
    LOADK(ka, 0);
    for (int kt = 0; kt < nkt; kt += 2) {
      if (kt + 1 < nkt) LOADK(kb2, kt + 1);
      P1TILE(ka, kt);
      if (kt + 1 >= nkt) break;
      if (kt + 2 < nkt) LOADK(ka, kt + 2);
      P1TILE(kb2, kt + 1);
    }
  }

  // butterfly combine across the 16 lanes sharing each row
#pragma unroll
  for (int off = 1; off < 16; off <<= 1)
#pragma unroll
    for (int r = 0; r < 4; ++r) {
      float om = __shfl_xor(m[r], off, 64);
      float ol = __shfl_xor(lsum[r], off, 64);
      float mn = fmaxf(m[r], om);
      lsum[r] = lsum[r] * __expf(m[r] - mn) + ol * __expf(om - mn);
      m[r] = mn;
    }

  if (ll == 0) {
    float2* mlb = mlbuf + (size_t)(b * NH + h) * S_LEN;
#pragma unroll
    for (int r = 0; r < 4; ++r)
      mlb[rowg[r]] = make_float2(m[r], 1.f / lsum[r]);
  }

  // zero-fill masked columns (must overwrite 0xAA poison)
  float* pbase = attnw + ((size_t)(b * NH + h)) * S_LEN * S_LEN;
  const int zc = nkt * 64;
  for (int rr = 0; rr < 16; ++rr) {
    float* dst = pbase + (size_t)(q0 + rr) * S_LEN;
    for (int c = zc + l * 4; c < S_LEN; c += 256)
      *(float4*)(dst + c) = make_float4(0.f, 0.f, 0.f, 0.f);
  }
}

// ---------------- attn pass 2: P write + PV ----------------
// Register double-buffered K prefetch; V loaded BEFORE this tile's P stores
// so counted vmcnt leaves stores in flight (no FIFO serialization).
__global__ __launch_bounds__(256, 2)
void attn_p2(const unsigned short* __restrict__ Qp,
             const unsigned short* __restrict__ Kp,
             const unsigned short* __restrict__ VTp,
             const float2* __restrict__ mlbuf,
             float* __restrict__ attnw,
             unsigned short* __restrict__ ctx) {
  const int idx = blockIdx.x;
  const int qt = 31 - idx / (NH * BATCH);
  const int hb = idx % (NH * BATCH);
  const int h = hb >> 1, b = hb & 1;
  const int tid = threadIdx.x, w = tid >> 6, l = tid & 63;
  const int lg = l >> 4, ll = l & 15;
  __shared__ unsigned short plds[4][1024];  // 16x64 bf16 per wave (private)
  char* plb = (char*)&plds[w][0];

  const unsigned short* kbp = Kp + (size_t)b * S_LEN * DMODEL + h * 64;
  const unsigned short* vbp = VTp + ((size_t)(b * NH + h)) * 64 * S_LEN;
  float* pbase = attnw + ((size_t)(b * NH + h)) * S_LEN * S_LEN;

  const int q0 = qt * 64 + w * 16;
  const int nkt = qt + 1;

  bf16x8 qf[2];
  {
    const unsigned short* qb =
        Qp + (size_t)(b * S_LEN + q0 + ll) * DMODEL + h * 64 + lg * 8;
    qf[0] = *(const bf16x8*)qb;
    qf[1] = *(const bf16x8*)(qb + 32);
  }
  int rowg[4];
#pragma unroll
  for (int r = 0; r < 4; ++r) rowg[r] = q0 + lg * 4 + r;

  float m[4], linv[4];
  {
    const float2* mlb = mlbuf + (size_t)(b * NH + h) * S_LEN;
#pragma unroll
    for (int r = 0; r < 4; ++r) {
      float2 t = mlb[rowg[r]];
      m[r] = t.x;
      linv[r] = t.y;
    }
  }

  f32x4 cacc[4];
#pragma unroll
  for (int nb = 0; nb < 4; ++nb) cacc[nb] = (f32x4){0.f, 0.f, 0.f, 0.f};

  auto LOADK = [&](bf16x8* kf, int kt) {
#pragma unroll
    for (int t = 0; t < 2; ++t)
#pragma unroll
      for (int nb = 0; nb < 4; ++nb)
        kf[t * 4 + nb] = *(const bf16x8*)(kbp +
            (size_t)(kt * 64 + nb * 16 + ll) * DMODEL + t * 32 + lg * 8);
  };
  auto LOADV = [&](bf16x8* vf, int kt) {
#pragma unroll
    for (int t = 0; t < 2; ++t)
#pragma unroll
      for (int nb = 0; nb < 4; ++nb)
        vf[t * 4 + nb] = *(const bf16x8*)(vbp +
            (size_t)(nb * 16 + ll) * S_LEN + kt * 64 + t * 32 + lg * 8);
  };

  auto P2TILE = [&](const bf16x8* kf, const bf16x8* vf, int kt) {
    f32x4 s[4];
#pragma unroll
    for (int nb = 0; nb < 4; ++nb) s[nb] = (f32x4){0.f, 0.f, 0.f, 0.f};
#pragma unroll
    for (int t = 0; t < 2; ++t)
#pragma unroll
      for (int nb = 0; nb < 4; ++nb)
        s[nb] = __builtin_amdgcn_mfma_f32_16x16x32_bf16(qf[t], kf[t * 4 + nb],
                                                        s[nb], 0, 0, 0);
#pragma unroll
    for (int nb = 0; nb < 4; ++nb) {
      const int col = kt * 64 + nb * 16 + ll;
#pragma unroll
      for (int r = 0; r < 4; ++r) {
        float p = (col <= rowg[r]) ? __expf(s[nb][r] - m[r]) * linv[r] : 0.f;
        pbase[(size_t)rowg[r] * S_LEN + col] = p;
        const int rl = lg * 4 + r;
        const int bo = ((rl * 64 + nb * 16 + ll) * 2) ^ ((rl & 7) << 4);
        *(unsigned short*)(plb + bo) = f2bf(p);
      }
    }
    // wave-private LDS round-trip (compiler lgkmcnt orders write->read)
    bf16x8 pf[2];
#pragma unroll
    for (int t = 0; t < 2; ++t) {
      const int bo = ((ll * 64 + t * 32 + lg * 8) * 2) ^ ((ll & 7) << 4);
      pf[t] = *(const bf16x8*)(plb + bo);
    }
#pragma unroll
    for (int t = 0; t < 2; ++t)
#pragma unroll
      for (int nb = 0; nb < 4; ++nb)
        cacc[nb] = __builtin_amdgcn_mfma_f32_16x16x32_bf16(
            pf[t], vf[t * 4 + nb], cacc[nb], 0, 0, 0);
  };

  {
    bf16x8 ka[8], kb2[8], vf[8];
    LOADK(ka, 0);
    for (int kt = 0; kt < nkt; kt += 2) {
      LOADV(vf, kt);
      if (kt + 1 < nkt) LOADK(kb2, kt + 1);
      P2TILE(ka, vf, kt);
      if (kt + 1 >= nkt) break;
      LOADV(vf, kt + 1);
      if (kt + 2 < nkt) LOADK(ka, kt + 2);
      P2TILE(kb2, vf, kt + 1);
    }
  }

  // context write (bf16, (B,S,D) layout)
#pragma unroll
  for (int nb = 0; nb < 4; ++nb)
#pragma unroll
    for (int r = 0; r < 4; ++r)
      ctx[(size_t)(b * S_LEN + rowg[r]) * DMODEL + h * 64 + nb * 16 + ll] =
          f2bf(cacc[nb][r]);
}

extern "C" void kernel_launch(void* const* d_in, const int* in_sizes, int n_in,
                              void* d_out, int out_size, void* d_ws, size_t ws_size,
                              hipStream_t stream) {
  const float* q_in = (const float*)d_in[0];
  const float* k_in = (const float*)d_in[1];
  const float* v_in = (const float*)d_in[2];
  // d_in[3] = mask: causal triu(k=1), hardcoded in attn kernels
  const float* wq = (const float*)d_in[4];
  const float* wk = (const float*)d_in[5];
  const float* wv = (const float*)d_in[6];
  const float* wo = (const float*)d_in[7];

  const int BSD = BATCH * S_LEN * DMODEL;  // 3145728
  const int DD = DMODEL * DMODEL;          // 589824
  const int M = BATCH * S_LEN;             // 4096

  char* ws = (char*)d_ws;
  unsigned short* qbf = (unsigned short*)ws;  ws += (size_t)BSD * 2;
  unsigned short* kbf = (unsigned short*)ws;  ws += (size_t)BSD * 2;
  unsigned short* vbf = (unsigned short*)ws;  ws += (size_t)BSD * 2;
  unsigned short* wqb = (unsigned short*)ws;  ws += (size_t)DD * 2;   // contiguous
  unsigned short* wkb = (unsigned short*)ws;  ws += (size_t)DD * 2;   //  W3 =
  unsigned short* wvb = (unsigned short*)ws;  ws += (size_t)DD * 2;   //  [2304][768]
  unsigned short* wob = (unsigned short*)ws;  ws += (size_t)DD * 2;
  unsigned short* Qs  = (unsigned short*)ws;  ws += (size_t)BSD * 2;
  unsigned short* Ks  = (unsigned short*)ws;  ws += (size_t)BSD * 2;
  unsigned short* VT  = (unsigned short*)ws;  ws += (size_t)BSD * 2;
  unsigned short* ctx = (unsigned short*)ws;  ws += (size_t)BSD * 2;
  float2* mlbuf = (float2*)ws;                ws += (size_t)M * NH * sizeof(float2);
  (void)wkb; (void)wvb;

  float* out_proj = (float*)d_out;
  float* attnw = (float*)d_out + BSD;

  cvt3_kernel<<<3 * N8_BSD / 256, 256, 0, stream>>>(q_in, k_in, v_in, qbf);
  cvt4_kernel<<<4 * N8_DD / 256, 256, 0, stream>>>(wq, wk, wv, wo, wqb);

  gemm_qkv<<<dim3(M / 128, 2304 / 64), 256, 0, stream>>>(qbf, kbf, vbf, wqb,
                                                         Qs, Ks, VT);

  attn_ml<<<32 * NH * BATCH, 256, 0, stream>>>(Qs, Ks, mlbuf, attnw);
  attn_p2<<<32 * NH * BATCH, 256, 0, stream>>>(Qs, Ks, VT, mlbuf, attnw, ctx);

  gemm_proj<<<dim3(M / 128, DMODEL / 64), 256, 0, stream>>>(ctx, wob, out_proj);
}

// Round 5
// 282.000 us; speedup vs baseline: 1.3460x; 1.0033x over previous
//
#include <hip/hip_runtime.h>

#define BATCH 2
#define S_LEN 2048
#define NH 12
#define DMODEL 768
// DK = 64, scale = 1/8

#define N8_BSD (BATCH * S_LEN * DMODEL / 8)  // 393216
#define N8_DD (DMODEL * DMODEL / 8)          // 73728

typedef __attribute__((ext_vector_type(8))) short bf16x8;
typedef __attribute__((ext_vector_type(4))) float f32x4;
typedef __attribute__((ext_vector_type(4))) unsigned short us4;

__device__ __forceinline__ unsigned short f2bf(float f) {
  union { float f; unsigned int u; } v; v.f = f;
  unsigned int r = v.u + 0x7fffu + ((v.u >> 16) & 1u);  // RNE
  return (unsigned short)(r >> 16);
}

// ------- f32 -> bf16 converts (8 elems/thread); cvt3 also zeroes ctx1 -------
__global__ void cvt3_kernel(const float* __restrict__ s0,
                            const float* __restrict__ s1,
                            const float* __restrict__ s2,
                            unsigned short* __restrict__ dst,
                            float* __restrict__ ctx1) {
  int i = blockIdx.x * blockDim.x + threadIdx.x;  // 0 .. 3*N8_BSD-1 (exact)
  int j = i / N8_BSD;
  int k = i - j * N8_BSD;
  const float* s = (j == 0) ? s0 : (j == 1) ? s1 : s2;
  const float4* sp = (const float4*)s;
  float4 a = sp[k * 2], b = sp[k * 2 + 1];
  us4 o0 = { f2bf(a.x), f2bf(a.y), f2bf(a.z), f2bf(a.w) };
  us4 o1 = { f2bf(b.x), f2bf(b.y), f2bf(b.z), f2bf(b.w) };
  us4* d = (us4*)dst;
  d[i * 2] = o0;
  d[i * 2 + 1] = o1;
  if (j == 0) {  // zero ctx1 partial buffer (BSD f32 = exactly this segment)
    float4 z = make_float4(0.f, 0.f, 0.f, 0.f);
    float4* c = (float4*)ctx1;
    c[k * 2] = z;
    c[k * 2 + 1] = z;
  }
}

__global__ void cvt4_kernel(const float* __restrict__ s0,
                            const float* __restrict__ s1,
                            const float* __restrict__ s2,
                            const float* __restrict__ s3,
                            unsigned short* __restrict__ dst) {
  int i = blockIdx.x * blockDim.x + threadIdx.x;  // 0 .. 4*N8_DD-1 (exact)
  int j = i / N8_DD;
  int k = i - j * N8_DD;
  const float* s = (j == 0) ? s0 : (j == 1) ? s1 : (j == 2) ? s2 : s3;
  const float4* sp = (const float4*)s;
  float4 a = sp[k * 2], b = sp[k * 2 + 1];
  us4 o0 = { f2bf(a.x), f2bf(a.y), f2bf(a.z), f2bf(a.w) };
  us4 o1 = { f2bf(b.x), f2bf(b.y), f2bf(b.z), f2bf(b.w) };
  us4* d = (us4*)dst;
  d[i * 2] = o0;
  d[i * 2 + 1] = o1;
}

// ------- reduce: ctx_bf16 = f2bf(ctx0 + ctx1), 4 elems/thread -------
__global__ void ctx_reduce(const float* __restrict__ c0,
                           const float* __restrict__ c1,
                           unsigned short* __restrict__ o) {
  int i = blockIdx.x * blockDim.x + threadIdx.x;  // 0 .. BSD/4-1
  float4 a = ((const float4*)c0)[i];
  float4 b = ((const float4*)c1)[i];
  us4 r = { f2bf(a.x + b.x), f2bf(a.y + b.y), f2bf(a.z + b.z), f2bf(a.w + b.w) };
  ((us4*)o)[i] = r;
}

#define GLD_LDS16(g, l)                                                    \
  __builtin_amdgcn_global_load_lds(                                        \
      (const __attribute__((address_space(1))) unsigned int*)(g),          \
      (__attribute__((address_space(3))) unsigned int*)(l), 16, 0, 0)

// ---------------- fused QKV projection GEMM ----------------
// grid (32, 36): n0g = blockIdx.y*64 selects Q (0..767), K (768..1535),
// V (1536..2303). W3 = [2304][768] contiguous (wq;wk;wv). Tile 128x64, BK=64.
__global__ __launch_bounds__(256, 2)
void gemm_qkv(const unsigned short* __restrict__ Aq,
              const unsigned short* __restrict__ Ak,
              const unsigned short* __restrict__ Av,
              const unsigned short* __restrict__ W3,
              unsigned short* __restrict__ Qs,
              unsigned short* __restrict__ Ks,
              unsigned short* __restrict__ VT) {
  __shared__ unsigned short As[128 * 64];
  __shared__ unsigned short Bs[64 * 64];
  const int m0 = blockIdx.x * 128;
  const int n0g = blockIdx.y * 64;
  const int nblk = n0g / 768;         // 0=Q 1=K 2=V (uniform per block)
  const int n0 = n0g - nblk * 768;
  const unsigned short* A = (nblk == 0) ? Aq : (nblk == 1) ? Ak : Av;
  const unsigned short* Bw = W3 + (size_t)n0g * DMODEL;
  const int tid = threadIdx.x, w = tid >> 6, l = tid & 63;
  const int lg = l >> 4, ll = l & 15;
  const int wm = w >> 1, wn = w & 1;
  const int lr = l >> 3, lc = (l & 7) * 8;

  f32x4 acc[4][2];
#pragma unroll
  for (int i = 0; i < 4; ++i)
#pragma unroll
    for (int j = 0; j < 2; ++j) acc[i][j] = (f32x4){0.f, 0.f, 0.f, 0.f};

  for (int k0 = 0; k0 < DMODEL; k0 += 64) {
#pragma unroll
    for (int i = 0; i < 4; ++i) {
      const unsigned short* src =
          A + (size_t)(m0 + w * 32 + i * 8 + lr) * DMODEL + k0 + lc;
      GLD_LDS16(src, &As[(w * 32 + i * 8) * 64]);
    }
#pragma unroll
    for (int i = 0; i < 2; ++i) {
      const unsigned short* src =
          Bw + (size_t)(w * 16 + i * 8 + lr) * DMODEL + k0 + lc;
      GLD_LDS16(src, &Bs[(w * 16 + i * 8) * 64]);
    }
    __syncthreads();
#pragma unroll
    for (int t = 0; t < 2; ++t) {
      bf16x8 af[4], bf[2];
#pragma unroll
      for (int mi = 0; mi < 4; ++mi)
        af[mi] = *(const bf16x8*)&As[(wm * 64 + mi * 16 + ll) * 64 + t * 32 + lg * 8];
#pragma unroll
      for (int ni = 0; ni < 2; ++ni)
        bf[ni] = *(const bf16x8*)&Bs[(wn * 32 + ni * 16 + ll) * 64 + t * 32 + lg * 8];
#pragma unroll
      for (int mi = 0; mi < 4; ++mi)
#pragma unroll
        for (int ni = 0; ni < 2; ++ni)
          acc[mi][ni] = __builtin_amdgcn_mfma_f32_16x16x32_bf16(
              af[mi], bf[ni], acc[mi][ni], 0, 0, 0);
    }
    __syncthreads();
  }

  if (nblk < 2) {  // Q or K: row-major [4096][768]; Q scaled by 1/8
    unsigned short* o = nblk ? Ks : Qs;
    const float sc = nblk ? 1.f : 0.125f;
#pragma unroll
    for (int mi = 0; mi < 4; ++mi)
#pragma unroll
      for (int ni = 0; ni < 2; ++ni) {
        const int col = n0 + wn * 32 + ni * 16 + ll;
        const int rowb = m0 + wm * 64 + mi * 16 + lg * 4;
#pragma unroll
        for (int r = 0; r < 4; ++r)
          o[(size_t)(rowb + r) * 768 + col] = f2bf(acc[mi][ni][r] * sc);
      }
  } else {  // V^T: (B,H,64,S)
#pragma unroll
    for (int mi = 0; mi < 4; ++mi)
#pragma unroll
      for (int ni = 0; ni < 2; ++ni) {
        const int col = n0 + wn * 32 + ni * 16 + ll;
        const int row = m0 + wm * 64 + mi * 16 + lg * 4;
        const int bb = row >> 11, sidx = row & (S_LEN - 1);
        const size_t base =
            ((size_t)(bb * NH + (col >> 6)) * 64 + (col & 63)) * S_LEN + sidx;
        us4 pk = { f2bf(acc[mi][ni][0]), f2bf(acc[mi][ni][1]),
                   f2bf(acc[mi][ni][2]), f2bf(acc[mi][ni][3]) };
        *(us4*)&VT[base] = pk;
      }
  }
}

// ---------------- output projection GEMM (f32 out) ----------------
__global__ __launch_bounds__(256, 2)
void gemm_proj(const unsigned short* __restrict__ A,
               const unsigned short* __restrict__ Bw,
               float* __restrict__ o) {
  __shared__ unsigned short As[128 * 64];
  __shared__ unsigned short Bs[64 * 64];
  const int m0 = blockIdx.x * 128, n0 = blockIdx.y * 64;
  const int tid = threadIdx.x, w = tid >> 6, l = tid & 63;
  const int lg = l >> 4, ll = l & 15;
  const int wm = w >> 1, wn = w & 1;
  const int lr = l >> 3, lc = (l & 7) * 8;

  f32x4 acc[4][2];
#pragma unroll
  for (int i = 0; i < 4; ++i)
#pragma unroll
    for (int j = 0; j < 2; ++j) acc[i][j] = (f32x4){0.f, 0.f, 0.f, 0.f};

  for (int k0 = 0; k0 < DMODEL; k0 += 64) {
#pragma unroll
    for (int i = 0; i < 4; ++i) {
      const unsigned short* src =
          A + (size_t)(m0 + w * 32 + i * 8 + lr) * DMODEL + k0 + lc;
      GLD_LDS16(src, &As[(w * 32 + i * 8) * 64]);
    }
#pragma unroll
    for (int i = 0; i < 2; ++i) {
      const unsigned short* src =
          Bw + (size_t)(n0 + w * 16 + i * 8 + lr) * DMODEL + k0 + lc;
      GLD_LDS16(src, &Bs[(w * 16 + i * 8) * 64]);
    }
    __syncthreads();
#pragma unroll
    for (int t = 0; t < 2; ++t) {
      bf16x8 af[4], bf[2];
#pragma unroll
      for (int mi = 0; mi < 4; ++mi)
        af[mi] = *(const bf16x8*)&As[(wm * 64 + mi * 16 + ll) * 64 + t * 32 + lg * 8];
#pragma unroll
      for (int ni = 0; ni < 2; ++ni)
        bf[ni] = *(const bf16x8*)&Bs[(wn * 32 + ni * 16 + ll) * 64 + t * 32 + lg * 8];
#pragma unroll
      for (int mi = 0; mi < 4; ++mi)
#pragma unroll
        for (int ni = 0; ni < 2; ++ni)
          acc[mi][ni] = __builtin_amdgcn_mfma_f32_16x16x32_bf16(
              af[mi], bf[ni], acc[mi][ni], 0, 0, 0);
    }
    __syncthreads();
  }

#pragma unroll
  for (int mi = 0; mi < 4; ++mi)
#pragma unroll
    for (int ni = 0; ni < 2; ++ni) {
      const int col = n0 + wn * 32 + ni * 16 + ll;
      const int rowb = m0 + wm * 64 + mi * 16 + lg * 4;
#pragma unroll
      for (int r = 0; r < 4; ++r)
        o[(size_t)(rowb + r) * DMODEL + col] = acc[mi][ni][r];
    }
}

// ---------------- attn pass 1: online (m, 1/l) only ----------------
// One WG per (q-tile, h, b); 4 waves; wave w owns rows qt*64+w*16..+16.
// Register double-buffered K prefetch; per-lane online (m,l); one butterfly.
__global__ __launch_bounds__(256, 3)
void attn_ml(const unsigned short* __restrict__ Qp,
             const unsigned short* __restrict__ Kp,
             float2* __restrict__ mlbuf) {
  const int idx = blockIdx.x;
  const int qt = 31 - idx / (NH * BATCH);  // heavy tiles first
  const int hb = idx % (NH * BATCH);
  const int h = hb >> 1, b = hb & 1;
  const int tid = threadIdx.x, w = tid >> 6, l = tid & 63;
  const int lg = l >> 4, ll = l & 15;

  const unsigned short* kbp = Kp + (size_t)b * S_LEN * DMODEL + h * 64;
  const int q0 = qt * 64 + w * 16;
  const int nkt = qt + 1;

  bf16x8 qf[2];
  {
    const unsigned short* qb =
        Qp + (size_t)(b * S_LEN + q0 + ll) * DMODEL + h * 64 + lg * 8;
    qf[0] = *(const bf16x8*)qb;
    qf[1] = *(const bf16x8*)(qb + 32);
  }
  int rowg[4];
#pragma unroll
  for (int r = 0; r < 4; ++r) rowg[r] = q0 + lg * 4 + r;

  float m[4], lsum[4];
#pragma unroll
  for (int r = 0; r < 4; ++r) { m[r] = -1e30f; lsum[r] = 0.f; }

  auto LOADK = [&](bf16x8* kf, int kt) {
#pragma unroll
    for (int t = 0; t < 2; ++t)
#pragma unroll
      for (int nb = 0; nb < 4; ++nb)
        kf[t * 4 + nb] = *(const bf16x8*)(kbp +
            (size_t)(kt * 64 + nb * 16 + ll) * DMODEL + t * 32 + lg * 8);
  };

  auto P1TILE = [&](const bf16x8* kf, int kt) {
    f32x4 s[4];
#pragma unroll
    for (int nb = 0; nb < 4; ++nb) s[nb] = (f32x4){0.f, 0.f, 0.f, 0.f};
#pragma unroll
    for (int t = 0; t < 2; ++t)
#pragma unroll
      for (int nb = 0; nb < 4; ++nb)
        s[nb] = __builtin_amdgcn_mfma_f32_16x16x32_bf16(qf[t], kf[t * 4 + nb],
                                                        s[nb], 0, 0, 0);
    if (kt == nkt - 1) {  // diagonal: causal mask
#pragma unroll
      for (int nb = 0; nb < 4; ++nb) {
        const int col = kt * 64 + nb * 16 + ll;
#pragma unroll
        for (int r = 0; r < 4; ++r)
          if (col > rowg[r]) s[nb][r] = -1e30f;
      }
    }
#pragma unroll
    for (int r = 0; r < 4; ++r) {
      float tm = fmaxf(fmaxf(s[0][r], s[1][r]), fmaxf(s[2][r], s[3][r]));
      float mn = fmaxf(m[r], tm);
      float te = __expf(s[0][r] - mn) + __expf(s[1][r] - mn) +
                 __expf(s[2][r] - mn) + __expf(s[3][r] - mn);
      lsum[r] = lsum[r] * __expf(m[r] - mn) + te;
      m[r] = mn;
    }
  };

  {
    bf16x8 ka[8], kb2[8];
    LOADK(ka, 0);
    for (int kt = 0; kt < nkt; kt += 2) {
      if (kt + 1 < nkt) LOADK(kb2, kt + 1);
      P1TILE(ka, kt);
      if (kt + 1 >= nkt) break;
      if (kt + 2 < nkt) LOADK(ka, kt + 2);
      P1TILE(kb2, kt + 1);
    }
  }

  // butterfly combine across the 16 lanes sharing each row
#pragma unroll
  for (int off = 1; off < 16; off <<= 1)
#pragma unroll
    for (int r = 0; r < 4; ++r) {
      float om = __shfl_xor(m[r], off, 64);
      float ol = __shfl_xor(lsum[r], off, 64);
      float mn = fmaxf(m[r], om);
      lsum[r] = lsum[r] * __expf(m[r] - mn) + ol * __expf(om - mn);
      m[r] = mn;
    }

  if (ll == 0) {
    float2* mlb = mlbuf + (size_t)(b * NH + h) * S_LEN;
#pragma unroll
    for (int r = 0; r < 4; ++r)
      mlb[rowg[r]] = make_float2(m[r], 1.f / lsum[r]);
  }
}

// ---------------- attn pass 2: chunked P write + PV ----------------
// Grid: 64 slots x 24 (h,b). Each slot = (chunk of 16 k-tiles, q-tile),
// heavy-first. Covers the FULL row range incl. zero region. Pipeline per
// tile: QK -> exp -> LDS roundtrip -> PV -> issue next K+V loads -> stores,
// so loads always precede stores in the vmcnt FIFO (no store-drain stalls).
__global__ __launch_bounds__(256, 2)
void attn_p2(const unsigned short* __restrict__ Qp,
             const unsigned short* __restrict__ Kp,
             const unsigned short* __restrict__ VTp,
             const float2* __restrict__ mlbuf,
             float* __restrict__ attnw,
             float* __restrict__ ctx0,
             float* __restrict__ ctx1) {
  const int idx = blockIdx.x;
  const int slot = idx / (NH * BATCH);
  const int hb = idx % (NH * BATCH);
  const int h = hb >> 1, b = hb & 1;
  // slot -> (chunk, qt), sorted by value-tile count desc
  int qt, ck;
  if (slot <= 16)      { ck = 0; qt = 15 + slot; }
  else if (slot == 17) { ck = 1; qt = 31; }
  else if (slot < 48)  { int u = slot - 18; int k = 15 - (u >> 1);
                         if (u & 1) { ck = 1; qt = k + 15; } else { ck = 0; qt = k - 1; } }
  else                 { ck = 1; qt = slot - 48; }

  const int ktlo = ck * 16;
  const int kthi = (qt < ktlo + 15) ? qt : (ktlo + 15);  // last value tile
  const bool hasval = (ktlo <= qt);

  const int tid = threadIdx.x, w = tid >> 6, l = tid & 63;
  const int lg = l >> 4, ll = l & 15;
  __shared__ unsigned short plds[4][1024];  // 16x64 bf16 per wave (private)
  char* plb = (char*)&plds[w][0];

  const unsigned short* kbp = Kp + (size_t)b * S_LEN * DMODEL + h * 64;
  const unsigned short* vbp = VTp + ((size_t)(b * NH + h)) * 64 * S_LEN;
  float* pbase = attnw + ((size_t)(b * NH + h)) * S_LEN * S_LEN;

  const int q0 = qt * 64 + w * 16;
  int rowg[4];
#pragma unroll
  for (int r = 0; r < 4; ++r) rowg[r] = q0 + lg * 4 + r;

  if (hasval) {
    bf16x8 qf[2];
    {
      const unsigned short* qb =
          Qp + (size_t)(b * S_LEN + q0 + ll) * DMODEL + h * 64 + lg * 8;
      qf[0] = *(const bf16x8*)qb;
      qf[1] = *(const bf16x8*)(qb + 32);
    }
    float m[4], linv[4];
    {
      const float2* mlb = mlbuf + (size_t)(b * NH + h) * S_LEN;
#pragma unroll
      for (int r = 0; r < 4; ++r) {
        float2 t = mlb[rowg[r]];
        m[r] = t.x;
        linv[r] = t.y;
      }
    }

    f32x4 cacc[4];
#pragma unroll
    for (int nb = 0; nb < 4; ++nb) cacc[nb] = (f32x4){0.f, 0.f, 0.f, 0.f};

    bf16x8 kf[8], vf[8];
#pragma unroll
    for (int t = 0; t < 2; ++t)
#pragma unroll
      for (int nb = 0; nb < 4; ++nb) {
        kf[t * 4 + nb] = *(const bf16x8*)(kbp +
            (size_t)(ktlo * 64 + nb * 16 + ll) * DMODEL + t * 32 + lg * 8);
        vf[t * 4 + nb] = *(const bf16x8*)(vbp +
            (size_t)(nb * 16 + ll) * S_LEN + ktlo * 64 + t * 32 + lg * 8);
      }

    for (int kt = ktlo; kt <= kthi; ++kt) {
      // QK^T
      f32x4 s[4];
#pragma unroll
      for (int nb = 0; nb < 4; ++nb) s[nb] = (f32x4){0.f, 0.f, 0.f, 0.f};
#pragma unroll
      for (int t = 0; t < 2; ++t)
#pragma unroll
        for (int nb = 0; nb < 4; ++nb)
          s[nb] = __builtin_amdgcn_mfma_f32_16x16x32_bf16(qf[t], kf[t * 4 + nb],
                                                          s[nb], 0, 0, 0);
      // p = softmax numerator * 1/l  (masked -> exact 0); keep in s[]
#pragma unroll
      for (int nb = 0; nb < 4; ++nb) {
        const int col = kt * 64 + nb * 16 + ll;
#pragma unroll
        for (int r = 0; r < 4; ++r) {
          float p = (col <= rowg[r]) ? __expf(s[nb][r] - m[r]) * linv[r] : 0.f;
          s[nb][r] = p;
          const int rl = lg * 4 + r;
          const int bo = ((rl * 64 + nb * 16 + ll) * 2) ^ ((rl & 7) << 4);
          *(unsigned short*)(plb + bo) = f2bf(p);
        }
      }
      // wave-private LDS roundtrip -> A-fragments
      bf16x8 pf[2];
#pragma unroll
      for (int t = 0; t < 2; ++t) {
        const int bo = ((ll * 64 + t * 32 + lg * 8) * 2) ^ ((ll & 7) << 4);
        pf[t] = *(const bf16x8*)(plb + bo);
      }
      // PV (uses current vf)
#pragma unroll
      for (int t = 0; t < 2; ++t)
#pragma unroll
        for (int nb = 0; nb < 4; ++nb)
          cacc[nb] = __builtin_amdgcn_mfma_f32_16x16x32_bf16(
              pf[t], vf[t * 4 + nb], cacc[nb], 0, 0, 0);
      // issue next tile's loads BEFORE this tile's stores (FIFO decoupling)
      if (kt < kthi) {
#pragma unroll
        for (int t = 0; t < 2; ++t)
#pragma unroll
          for (int nb = 0; nb < 4; ++nb) {
            kf[t * 4 + nb] = *(const bf16x8*)(kbp +
                (size_t)((kt + 1) * 64 + nb * 16 + ll) * DMODEL + t * 32 + lg * 8);
            vf[t * 4 + nb] = *(const bf16x8*)(vbp +
                (size_t)(nb * 16 + ll) * S_LEN + (kt + 1) * 64 + t * 32 + lg * 8);
          }
      }
      // P stores (retire asynchronously; nothing waits on them)
#pragma unroll
      for (int nb = 0; nb < 4; ++nb) {
        const int col = kt * 64 + nb * 16 + ll;
#pragma unroll
        for (int r = 0; r < 4; ++r)
          pbase[(size_t)rowg[r] * S_LEN + col] = s[nb][r];
      }
    }

    // PV partial -> ctx0 (chunk 0) or ctx1 (chunk 1)
    float* co = ck ? ctx1 : ctx0;
#pragma unroll
    for (int nb = 0; nb < 4; ++nb)
#pragma unroll
      for (int r = 0; r < 4; ++r)
        co[(size_t)(b * S_LEN + rowg[r]) * DMODEL + h * 64 + nb * 16 + ll] =
            cacc[nb][r];
  }

  // zero-fill masked columns inside this chunk (overwrite 0xAA poison)
  const int zs = ((qt + 1) * 64 > ktlo * 64) ? (qt + 1) * 64 : ktlo * 64;
  const int ze = (ktlo + 16) * 64;
  if (zs < ze) {
    for (int rr = 0; rr < 16; ++rr) {
      float* dst = pbase + (size_t)(q0 + rr) * S_LEN;
      for (int c = zs + l * 4; c < ze; c += 256)
        *(float4*)(dst + c) = make_float4(0.f, 0.f, 0.f, 0.f);
    }
  }
}

extern "C" void kernel_launch(void* const* d_in, const int* in_sizes, int n_in,
                              void* d_out, int out_size, void* d_ws, size_t ws_size,
                              hipStream_t stream) {
  const float* q_in = (const float*)d_in[0];
  const float* k_in = (const float*)d_in[1];
  const float* v_in = (const float*)d_in[2];
  // d_in[3] = mask: causal triu(k=1), hardcoded in attn kernels
  const float* wq = (const float*)d_in[4];
  const float* wk = (const float*)d_in[5];
  const float* wv = (const float*)d_in[6];
  const float* wo = (const float*)d_in[7];

  const int BSD = BATCH * S_LEN * DMODEL;  // 3145728
  const int DD = DMODEL * DMODEL;          // 589824
  const int M = BATCH * S_LEN;             // 4096

  char* ws = (char*)d_ws;
  unsigned short* qbf = (unsigned short*)ws;  ws += (size_t)BSD * 2;
  unsigned short* kbf = (unsigned short*)ws;  ws += (size_t)BSD * 2;
  unsigned short* vbf = (unsigned short*)ws;  ws += (size_t)BSD * 2;
  unsigned short* wqb = (unsigned short*)ws;  ws += (size_t)DD * 2;   // contiguous
  unsigned short* wkb = (unsigned short*)ws;  ws += (size_t)DD * 2;   //  W3 =
  unsigned short* wvb = (unsigned short*)ws;  ws += (size_t)DD * 2;   //  [2304][768]
  unsigned short* wob = (unsigned short*)ws;  ws += (size_t)DD * 2;
  unsigned short* Qs  = (unsigned short*)ws;  ws += (size_t)BSD * 2;
  unsigned short* Ks  = (unsigned short*)ws;  ws += (size_t)BSD * 2;
  unsigned short* VT  = (unsigned short*)ws;  ws += (size_t)BSD * 2;
  unsigned short* ctx = (unsigned short*)ws;  ws += (size_t)BSD * 2;
  float* ctx0 = (float*)ws;                   ws += (size_t)BSD * 4;
  float* ctx1 = (float*)ws;                   ws += (size_t)BSD * 4;
  float2* mlbuf = (float2*)ws;                ws += (size_t)M * NH * sizeof(float2);
  (void)wkb; (void)wvb;

  float* out_proj = (float*)d_out;
  float* attnw = (float*)d_out + BSD;

  cvt3_kernel<<<3 * N8_BSD / 256, 256, 0, stream>>>(q_in, k_in, v_in, qbf, ctx1);
  cvt4_kernel<<<4 * N8_DD / 256, 256, 0, stream>>>(wq, wk, wv, wo, wqb);

  gemm_qkv<<<dim3(M / 128, 2304 / 64), 256, 0, stream>>>(qbf, kbf, vbf, wqb,
                                                         Qs, Ks, VT);

  attn_ml<<<32 * NH * BATCH, 256, 0, stream>>>(Qs, Ks, mlbuf);
  attn_p2<<<64 * NH * BATCH, 256, 0, stream>>>(Qs, Ks, VT, mlbuf, attnw,
                                               ctx0, ctx1);
  ctx_reduce<<<BSD / 4 / 256, 256, 0, stream>>>(ctx0, ctx1, ctx);

  gemm_proj<<<dim3(M / 128, DMODEL / 64), 256, 0, stream>>>(ctx, wob, out_proj);
}

// Round 6
// 271.851 us; speedup vs baseline: 1.3962x; 1.0373x over previous
//
#include <hip/hip_runtime.h>

#define BATCH 2
#define S_LEN 2048
#define NH 12
#define DMODEL 768
// DK = 64, scale = 1/8

#define N8_BSD (BATCH * S_LEN * DMODEL / 8)  // 393216
#define N8_DD (DMODEL * DMODEL / 8)          // 73728

typedef __attribute__((ext_vector_type(8))) short bf16x8;
typedef __attribute__((ext_vector_type(4))) float f32x4;
typedef __attribute__((ext_vector_type(4))) unsigned short us4;

__device__ __forceinline__ unsigned short f2bf(float f) {
  union { float f; unsigned int u; } v; v.f = f;
  unsigned int r = v.u + 0x7fffu + ((v.u >> 16) & 1u);  // RNE
  return (unsigned short)(r >> 16);
}

// ------- f32 -> bf16 converts (8 elems/thread); cvt3 also zeroes ctx1 -------
__global__ void cvt3_kernel(const float* __restrict__ s0,
                            const float* __restrict__ s1,
                            const float* __restrict__ s2,
                            unsigned short* __restrict__ dst,
                            float* __restrict__ ctx1) {
  int i = blockIdx.x * blockDim.x + threadIdx.x;  // 0 .. 3*N8_BSD-1 (exact)
  int j = i / N8_BSD;
  int k = i - j * N8_BSD;
  const float* s = (j == 0) ? s0 : (j == 1) ? s1 : s2;
  const float4* sp = (const float4*)s;
  float4 a = sp[k * 2], b = sp[k * 2 + 1];
  us4 o0 = { f2bf(a.x), f2bf(a.y), f2bf(a.z), f2bf(a.w) };
  us4 o1 = { f2bf(b.x), f2bf(b.y), f2bf(b.z), f2bf(b.w) };
  us4* d = (us4*)dst;
  d[i * 2] = o0;
  d[i * 2 + 1] = o1;
  if (j == 0) {  // zero ctx1 partial buffer (BSD f32 = exactly this segment)
    float4 z = make_float4(0.f, 0.f, 0.f, 0.f);
    float4* c = (float4*)ctx1;
    c[k * 2] = z;
    c[k * 2 + 1] = z;
  }
}

__global__ void cvt4_kernel(const float* __restrict__ s0,
                            const float* __restrict__ s1,
                            const float* __restrict__ s2,
                            const float* __restrict__ s3,
                            unsigned short* __restrict__ dst) {
  int i = blockIdx.x * blockDim.x + threadIdx.x;  // 0 .. 4*N8_DD-1 (exact)
  int j = i / N8_DD;
  int k = i - j * N8_DD;
  const float* s = (j == 0) ? s0 : (j == 1) ? s1 : (j == 2) ? s2 : s3;
  const float4* sp = (const float4*)s;
  float4 a = sp[k * 2], b = sp[k * 2 + 1];
  us4 o0 = { f2bf(a.x), f2bf(a.y), f2bf(a.z), f2bf(a.w) };
  us4 o1 = { f2bf(b.x), f2bf(b.y), f2bf(b.z), f2bf(b.w) };
  us4* d = (us4*)dst;
  d[i * 2] = o0;
  d[i * 2 + 1] = o1;
}

// ------- reduce: ctx_bf16 = f2bf(ctx0 + ctx1), 4 elems/thread -------
__global__ void ctx_reduce(const float* __restrict__ c0,
                           const float* __restrict__ c1,
                           unsigned short* __restrict__ o) {
  int i = blockIdx.x * blockDim.x + threadIdx.x;  // 0 .. BSD/4-1
  float4 a = ((const float4*)c0)[i];
  float4 b = ((const float4*)c1)[i];
  us4 r = { f2bf(a.x + b.x), f2bf(a.y + b.y), f2bf(a.z + b.z), f2bf(a.w + b.w) };
  ((us4*)o)[i] = r;
}

#define GLD_LDS16(g, l)                                                    \
  __builtin_amdgcn_global_load_lds(                                        \
      (const __attribute__((address_space(1))) unsigned int*)(g),          \
      (__attribute__((address_space(3))) unsigned int*)(l), 16, 0, 0)

// ---------------- fused QKV projection GEMM ----------------
// grid (32, 36): n0g = blockIdx.y*64 selects Q (0..767), K (768..1535),
// V (1536..2303). W3 = [2304][768] contiguous (wq;wk;wv). Tile 128x64, BK=64.
__global__ __launch_bounds__(256, 2)
void gemm_qkv(const unsigned short* __restrict__ Aq,
              const unsigned short* __restrict__ Ak,
              const unsigned short* __restrict__ Av,
              const unsigned short* __restrict__ W3,
              unsigned short* __restrict__ Qs,
              unsigned short* __restrict__ Ks,
              unsigned short* __restrict__ VT) {
  __shared__ unsigned short As[128 * 64];
  __shared__ unsigned short Bs[64 * 64];
  const int m0 = blockIdx.x * 128;
  const int n0g = blockIdx.y * 64;
  const int nblk = n0g / 768;         // 0=Q 1=K 2=V (uniform per block)
  const int n0 = n0g - nblk * 768;
  const unsigned short* A = (nblk == 0) ? Aq : (nblk == 1) ? Ak : Av;
  const unsigned short* Bw = W3 + (size_t)n0g * DMODEL;
  const int tid = threadIdx.x, w = tid >> 6, l = tid & 63;
  const int lg = l >> 4, ll = l & 15;
  const int wm = w >> 1, wn = w & 1;
  const int lr = l >> 3, lc = (l & 7) * 8;

  f32x4 acc[4][2];
#pragma unroll
  for (int i = 0; i < 4; ++i)
#pragma unroll
    for (int j = 0; j < 2; ++j) acc[i][j] = (f32x4){0.f, 0.f, 0.f, 0.f};

  for (int k0 = 0; k0 < DMODEL; k0 += 64) {
#pragma unroll
    for (int i = 0; i < 4; ++i) {
      const unsigned short* src =
          A + (size_t)(m0 + w * 32 + i * 8 + lr) * DMODEL + k0 + lc;
      GLD_LDS16(src, &As[(w * 32 + i * 8) * 64]);
    }
#pragma unroll
    for (int i = 0; i < 2; ++i) {
      const unsigned short* src =
          Bw + (size_t)(w * 16 + i * 8 + lr) * DMODEL + k0 + lc;
      GLD_LDS16(src, &Bs[(w * 16 + i * 8) * 64]);
    }
    __syncthreads();
#pragma unroll
    for (int t = 0; t < 2; ++t) {
      bf16x8 af[4], bf[2];
#pragma unroll
      for (int mi = 0; mi < 4; ++mi)
        af[mi] = *(const bf16x8*)&As[(wm * 64 + mi * 16 + ll) * 64 + t * 32 + lg * 8];
#pragma unroll
      for (int ni = 0; ni < 2; ++ni)
        bf[ni] = *(const bf16x8*)&Bs[(wn * 32 + ni * 16 + ll) * 64 + t * 32 + lg * 8];
#pragma unroll
      for (int mi = 0; mi < 4; ++mi)
#pragma unroll
        for (int ni = 0; ni < 2; ++ni)
          acc[mi][ni] = __builtin_amdgcn_mfma_f32_16x16x32_bf16(
              af[mi], bf[ni], acc[mi][ni], 0, 0, 0);
    }
    __syncthreads();
  }

  if (nblk < 2) {  // Q or K: row-major [4096][768]; Q scaled by 1/8
    unsigned short* o = nblk ? Ks : Qs;
    const float sc = nblk ? 1.f : 0.125f;
#pragma unroll
    for (int mi = 0; mi < 4; ++mi)
#pragma unroll
      for (int ni = 0; ni < 2; ++ni) {
        const int col = n0 + wn * 32 + ni * 16 + ll;
        const int rowb = m0 + wm * 64 + mi * 16 + lg * 4;
#pragma unroll
        for (int r = 0; r < 4; ++r)
          o[(size_t)(rowb + r) * 768 + col] = f2bf(acc[mi][ni][r] * sc);
      }
  } else {  // V^T: (B,H,64,S)
#pragma unroll
    for (int mi = 0; mi < 4; ++mi)
#pragma unroll
      for (int ni = 0; ni < 2; ++ni) {
        const int col = n0 + wn * 32 + ni * 16 + ll;
        const int row = m0 + wm * 64 + mi * 16 + lg * 4;
        const int bb = row >> 11, sidx = row & (S_LEN - 1);
        const size_t base =
            ((size_t)(bb * NH + (col >> 6)) * 64 + (col & 63)) * S_LEN + sidx;
        us4 pk = { f2bf(acc[mi][ni][0]), f2bf(acc[mi][ni][1]),
                   f2bf(acc[mi][ni][2]), f2bf(acc[mi][ni][3]) };
        *(us4*)&VT[base] = pk;
      }
  }
}

// ---------------- output projection GEMM (f32 out) ----------------
__global__ __launch_bounds__(256, 2)
void gemm_proj(const unsigned short* __restrict__ A,
               const unsigned short* __restrict__ Bw,
               float* __restrict__ o) {
  __shared__ unsigned short As[128 * 64];
  __shared__ unsigned short Bs[64 * 64];
  const int m0 = blockIdx.x * 128, n0 = blockIdx.y * 64;
  const int tid = threadIdx.x, w = tid >> 6, l = tid & 63;
  const int lg = l >> 4, ll = l & 15;
  const int wm = w >> 1, wn = w & 1;
  const int lr = l >> 3, lc = (l & 7) * 8;

  f32x4 acc[4][2];
#pragma unroll
  for (int i = 0; i < 4; ++i)
#pragma unroll
    for (int j = 0; j < 2; ++j) acc[i][j] = (f32x4){0.f, 0.f, 0.f, 0.f};

  for (int k0 = 0; k0 < DMODEL; k0 += 64) {
#pragma unroll
    for (int i = 0; i < 4; ++i) {
      const unsigned short* src =
          A + (size_t)(m0 + w * 32 + i * 8 + lr) * DMODEL + k0 + lc;
      GLD_LDS16(src, &As[(w * 32 + i * 8) * 64]);
    }
#pragma unroll
    for (int i = 0; i < 2; ++i) {
      const unsigned short* src =
          Bw + (size_t)(n0 + w * 16 + i * 8 + lr) * DMODEL + k0 + lc;
      GLD_LDS16(src, &Bs[(w * 16 + i * 8) * 64]);
    }
    __syncthreads();
#pragma unroll
    for (int t = 0; t < 2; ++t) {
      bf16x8 af[4], bf[2];
#pragma unroll
      for (int mi = 0; mi < 4; ++mi)
        af[mi] = *(const bf16x8*)&As[(wm * 64 + mi * 16 + ll) * 64 + t * 32 + lg * 8];
#pragma unroll
      for (int ni = 0; ni < 2; ++ni)
        bf[ni] = *(const bf16x8*)&Bs[(wn * 32 + ni * 16 + ll) * 64 + t * 32 + lg * 8];
#pragma unroll
      for (int mi = 0; mi < 4; ++mi)
#pragma unroll
        for (int ni = 0; ni < 2; ++ni)
          acc[mi][ni] = __builtin_amdgcn_mfma_f32_16x16x32_bf16(
              af[mi], bf[ni], acc[mi][ni], 0, 0, 0);
    }
    __syncthreads();
  }

#pragma unroll
  for (int mi = 0; mi < 4; ++mi)
#pragma unroll
    for (int ni = 0; ni < 2; ++ni) {
      const int col = n0 + wn * 32 + ni * 16 + ll;
      const int rowb = m0 + wm * 64 + mi * 16 + lg * 4;
#pragma unroll
      for (int r = 0; r < 4; ++r)
        o[(size_t)(rowb + r) * DMODEL + col] = acc[mi][ni][r];
    }
}

// ---------------- attn pass 1: online (m, 1/l) only ----------------
__global__ __launch_bounds__(256, 3)
void attn_ml(const unsigned short* __restrict__ Qp,
             const unsigned short* __restrict__ Kp,
             float2* __restrict__ mlbuf) {
  const int idx = blockIdx.x;
  const int qt = 31 - idx / (NH * BATCH);  // heavy tiles first
  const int hb = idx % (NH * BATCH);
  const int h = hb >> 1, b = hb & 1;
  const int tid = threadIdx.x, w = tid >> 6, l = tid & 63;
  const int lg = l >> 4, ll = l & 15;

  const unsigned short* kbp = Kp + (size_t)b * S_LEN * DMODEL + h * 64;
  const int q0 = qt * 64 + w * 16;
  const int nkt = qt + 1;

  bf16x8 qf[2];
  {
    const unsigned short* qb =
        Qp + (size_t)(b * S_LEN + q0 + ll) * DMODEL + h * 64 + lg * 8;
    qf[0] = *(const bf16x8*)qb;
    qf[1] = *(const bf16x8*)(qb + 32);
  }
  int rowg[4];
#pragma unroll
  for (int r = 0; r < 4; ++r) rowg[r] = q0 + lg * 4 + r;

  float m[4], lsum[4];
#pragma unroll
  for (int r = 0; r < 4; ++r) { m[r] = -1e30f; lsum[r] = 0.f; }

  auto LOADK = [&](bf16x8* kf, int kt) {
#pragma unroll
    for (int t = 0; t < 2; ++t)
#pragma unroll
      for (int nb = 0; nb < 4; ++nb)
        kf[t * 4 + nb] = *(const bf16x8*)(kbp +
            (size_t)(kt * 64 + nb * 16 + ll) * DMODEL + t * 32 + lg * 8);
  };

  auto P1TILE = [&](const bf16x8* kf, int kt) {
    f32x4 s[4];
#pragma unroll
    for (int nb = 0; nb < 4; ++nb) s[nb] = (f32x4){0.f, 0.f, 0.f, 0.f};
#pragma unroll
    for (int t = 0; t < 2; ++t)
#pragma unroll
      for (int nb = 0; nb < 4; ++nb)
        s[nb] = __builtin_amdgcn_mfma_f32_16x16x32_bf16(qf[t], kf[t * 4 + nb],
                                                        s[nb], 0, 0, 0);
    if (kt == nkt - 1) {  // diagonal: causal mask
#pragma unroll
      for (int nb = 0; nb < 4; ++nb) {
        const int col = kt * 64 + nb * 16 + ll;
#pragma unroll
        for (int r = 0; r < 4; ++r)
          if (col > rowg[r]) s[nb][r] = -1e30f;
      }
    }
#pragma unroll
    for (int r = 0; r < 4; ++r) {
      float tm = fmaxf(fmaxf(s[0][r], s[1][r]), fmaxf(s[2][r], s[3][r]));
      float mn = fmaxf(m[r], tm);
      float te = __expf(s[0][r] - mn) + __expf(s[1][r] - mn) +
                 __expf(s[2][r] - mn) + __expf(s[3][r] - mn);
      lsum[r] = lsum[r] * __expf(m[r] - mn) + te;
      m[r] = mn;
    }
  };

  {
    bf16x8 ka[8], kb2[8];
    LOADK(ka, 0);
    for (int kt = 0; kt < nkt; kt += 2) {
      if (kt + 1 < nkt) LOADK(kb2, kt + 1);
      P1TILE(ka, kt);
      if (kt + 1 >= nkt) break;
      if (kt + 2 < nkt) LOADK(ka, kt + 2);
      P1TILE(kb2, kt + 1);
    }
  }

  // butterfly combine across the 16 lanes sharing each row
#pragma unroll
  for (int off = 1; off < 16; off <<= 1)
#pragma unroll
    for (int r = 0; r < 4; ++r) {
      float om = __shfl_xor(m[r], off, 64);
      float ol = __shfl_xor(lsum[r], off, 64);
      float mn = fmaxf(m[r], om);
      lsum[r] = lsum[r] * __expf(m[r] - mn) + ol * __expf(om - mn);
      m[r] = mn;
    }

  if (ll == 0) {
    float2* mlb = mlbuf + (size_t)(b * NH + h) * S_LEN;
#pragma unroll
    for (int r = 0; r < 4; ++r)
      mlb[rowg[r]] = make_float2(m[r], 1.f / lsum[r]);
  }
}

// ---------------- attn pass 2: chunked P write + PV ----------------
// Grid: 64 slots x 24 (h,b). Each slot = (chunk of 16 k-tiles, q-tile).
// P and ctx stores are COALESCED full-cache-line dwordx4 via a wave-private
// 16x64 f32 LDS tile (avoids L2 write-allocate read amplification of
// partial-line scalar stores). Loads still precede stores in the vmcnt FIFO.
__global__ __launch_bounds__(256, 2)
void attn_p2(const unsigned short* __restrict__ Qp,
             const unsigned short* __restrict__ Kp,
             const unsigned short* __restrict__ VTp,
             const float2* __restrict__ mlbuf,
             float* __restrict__ attnw,
             float* __restrict__ ctx0,
             float* __restrict__ ctx1) {
  const int idx = blockIdx.x;
  const int slot = idx / (NH * BATCH);
  const int hb = idx % (NH * BATCH);
  const int h = hb >> 1, b = hb & 1;
  // slot -> (chunk, qt), sorted by value-tile count desc
  int qt, ck;
  if (slot <= 16)      { ck = 0; qt = 15 + slot; }
  else if (slot == 17) { ck = 1; qt = 31; }
  else if (slot < 48)  { int u = slot - 18; int k = 15 - (u >> 1);
                         if (u & 1) { ck = 1; qt = k + 15; } else { ck = 0; qt = k - 1; } }
  else                 { ck = 1; qt = slot - 48; }

  const int ktlo = ck * 16;
  const int kthi = (qt < ktlo + 15) ? qt : (ktlo + 15);  // last value tile
  const bool hasval = (ktlo <= qt);

  const int tid = threadIdx.x, w = tid >> 6, l = tid & 63;
  const int lg = l >> 4, ll = l & 15;
  __shared__ unsigned short plds[4][1024];  // 16x64 bf16 per wave (private)
  __shared__ float pf32[4][1024];           // 16x64 f32 per wave (private)
  char* plb = (char*)&plds[w][0];
  float* pfw = &pf32[w][0];

  const unsigned short* kbp = Kp + (size_t)b * S_LEN * DMODEL + h * 64;
  const unsigned short* vbp = VTp + ((size_t)(b * NH + h)) * 64 * S_LEN;
  float* pbase = attnw + ((size_t)(b * NH + h)) * S_LEN * S_LEN;

  const int q0 = qt * 64 + w * 16;
  int rowg[4];
#pragma unroll
  for (int r = 0; r < 4; ++r) rowg[r] = q0 + lg * 4 + r;

  if (hasval) {
    bf16x8 qf[2];
    {
      const unsigned short* qb =
          Qp + (size_t)(b * S_LEN + q0 + ll) * DMODEL + h * 64 + lg * 8;
      qf[0] = *(const bf16x8*)qb;
      qf[1] = *(const bf16x8*)(qb + 32);
    }
    float m[4], linv[4];
    {
      const float2* mlb = mlbuf + (size_t)(b * NH + h) * S_LEN;
#pragma unroll
      for (int r = 0; r < 4; ++r) {
        float2 t = mlb[rowg[r]];
        m[r] = t.x;
        linv[r] = t.y;
      }
    }

    f32x4 cacc[4];
#pragma unroll
    for (int nb = 0; nb < 4; ++nb) cacc[nb] = (f32x4){0.f, 0.f, 0.f, 0.f};

    bf16x8 kf[8], vf[8];
#pragma unroll
    for (int t = 0; t < 2; ++t)
#pragma unroll
      for (int nb = 0; nb < 4; ++nb) {
        kf[t * 4 + nb] = *(const bf16x8*)(kbp +
            (size_t)(ktlo * 64 + nb * 16 + ll) * DMODEL + t * 32 + lg * 8);
        vf[t * 4 + nb] = *(const bf16x8*)(vbp +
            (size_t)(nb * 16 + ll) * S_LEN + ktlo * 64 + t * 32 + lg * 8);
      }

    for (int kt = ktlo; kt <= kthi; ++kt) {
      // QK^T
      f32x4 s[4];
#pragma unroll
      for (int nb = 0; nb < 4; ++nb) s[nb] = (f32x4){0.f, 0.f, 0.f, 0.f};
#pragma unroll
      for (int t = 0; t < 2; ++t)
#pragma unroll
        for (int nb = 0; nb < 4; ++nb)
          s[nb] = __builtin_amdgcn_mfma_f32_16x16x32_bf16(qf[t], kf[t * 4 + nb],
                                                          s[nb], 0, 0, 0);
      // p (masked -> exact 0) -> bf16 LDS (PV frag) + f32 LDS (store staging)
#pragma unroll
      for (int nb = 0; nb < 4; ++nb) {
        const int col = kt * 64 + nb * 16 + ll;
#pragma unroll
        for (int r = 0; r < 4; ++r) {
          float p = (col <= rowg[r]) ? __expf(s[nb][r] - m[r]) * linv[r] : 0.f;
          const int rl = lg * 4 + r;
          const int bo = ((rl * 64 + nb * 16 + ll) * 2) ^ ((rl & 7) << 4);
          *(unsigned short*)(plb + bo) = f2bf(p);
          pfw[rl * 64 + ((nb * 16 + ll) ^ ((lg & 1) << 4))] = p;  // (row>>2)&1 swz
        }
      }
      // wave-private LDS roundtrip -> A-fragments
      bf16x8 pf[2];
#pragma unroll
      for (int t = 0; t < 2; ++t) {
        const int bo = ((ll * 64 + t * 32 + lg * 8) * 2) ^ ((ll & 7) << 4);
        pf[t] = *(const bf16x8*)(plb + bo);
      }
      // PV (uses current vf)
#pragma unroll
      for (int t = 0; t < 2; ++t)
#pragma unroll
        for (int nb = 0; nb < 4; ++nb)
          cacc[nb] = __builtin_amdgcn_mfma_f32_16x16x32_bf16(
              pf[t], vf[t * 4 + nb], cacc[nb], 0, 0, 0);
      // issue next tile's loads BEFORE this tile's stores (FIFO decoupling)
      if (kt < kthi) {
#pragma unroll
        for (int t = 0; t < 2; ++t)
#pragma unroll
          for (int nb = 0; nb < 4; ++nb) {
            kf[t * 4 + nb] = *(const bf16x8*)(kbp +
                (size_t)((kt + 1) * 64 + nb * 16 + ll) * DMODEL + t * 32 + lg * 8);
            vf[t * 4 + nb] = *(const bf16x8*)(vbp +
                (size_t)(nb * 16 + ll) * S_LEN + (kt + 1) * 64 + t * 32 + lg * 8);
          }
      }
      // coalesced P stores: 4 passes, each wave instr = 4 rows x 256B full lines
#pragma unroll
      for (int ps = 0; ps < 4; ++ps) {
        const int row = ps * 4 + lg;                       // (row>>2)&1 == ps&1
        const int cb = (ll * 4) ^ ((ps & 1) << 4);
        f32x4 pv = *(const f32x4*)&pfw[row * 64 + cb];
        *(f32x4*)&pbase[(size_t)(q0 + row) * S_LEN + kt * 64 + ll * 4] = pv;
      }
    }

    // PV partial -> ctx0/ctx1, coalesced via same f32 LDS tile
#pragma unroll
    for (int nb = 0; nb < 4; ++nb)
#pragma unroll
      for (int r = 0; r < 4; ++r) {
        const int rl = lg * 4 + r;
        pfw[rl * 64 + ((nb * 16 + ll) ^ ((lg & 1) << 4))] = cacc[nb][r];
      }
    float* co = ck ? ctx1 : ctx0;
#pragma unroll
    for (int ps = 0; ps < 4; ++ps) {
      const int row = ps * 4 + lg;
      const int cb = (ll * 4) ^ ((ps & 1) << 4);
      f32x4 cv = *(const f32x4*)&pfw[row * 64 + cb];
      *(f32x4*)&co[(size_t)(b * S_LEN + q0 + row) * DMODEL + h * 64 + ll * 4] = cv;
    }
  }

  // zero-fill masked columns inside this chunk (overwrite 0xAA poison)
  const int zs = ((qt + 1) * 64 > ktlo * 64) ? (qt + 1) * 64 : ktlo * 64;
  const int ze = (ktlo + 16) * 64;
  if (zs < ze) {
    for (int rr = 0; rr < 16; ++rr) {
      float* dst = pbase + (size_t)(q0 + rr) * S_LEN;
      for (int c = zs + l * 4; c < ze; c += 256)
        *(float4*)(dst + c) = make_float4(0.f, 0.f, 0.f, 0.f);
    }
  }
}

extern "C" void kernel_launch(void* const* d_in, const int* in_sizes, int n_in,
                              void* d_out, int out_size, void* d_ws, size_t ws_size,
                              hipStream_t stream) {
  const float* q_in = (const float*)d_in[0];
  const float* k_in = (const float*)d_in[1];
  const float* v_in = (const float*)d_in[2];
  // d_in[3] = mask: causal triu(k=1), hardcoded in attn kernels
  const float* wq = (const float*)d_in[4];
  const float* wk = (const float*)d_in[5];
  const float* wv = (const float*)d_in[6];
  const float* wo = (const float*)d_in[7];

  const int BSD = BATCH * S_LEN * DMODEL;  // 3145728
  const int DD = DMODEL * DMODEL;          // 589824
  const int M = BATCH * S_LEN;             // 4096

  char* ws = (char*)d_ws;
  unsigned short* qbf = (unsigned short*)ws;  ws += (size_t)BSD * 2;
  unsigned short* kbf = (unsigned short*)ws;  ws += (size_t)BSD * 2;
  unsigned short* vbf = (unsigned short*)ws;  ws += (size_t)BSD * 2;
  unsigned short* wqb = (unsigned short*)ws;  ws += (size_t)DD * 2;   // contiguous
  unsigned short* wkb = (unsigned short*)ws;  ws += (size_t)DD * 2;   //  W3 =
  unsigned short* wvb = (unsigned short*)ws;  ws += (size_t)DD * 2;   //  [2304][768]
  unsigned short* wob = (unsigned short*)ws;  ws += (size_t)DD * 2;
  unsigned short* Qs  = (unsigned short*)ws;  ws += (size_t)BSD * 2;
  unsigned short* Ks  = (unsigned short*)ws;  ws += (size_t)BSD * 2;
  unsigned short* VT  = (unsigned short*)ws;  ws += (size_t)BSD * 2;
  unsigned short* ctx = (unsigned short*)ws;  ws += (size_t)BSD * 2;
  float* ctx0 = (float*)ws;                   ws += (size_t)BSD * 4;
  float* ctx1 = (float*)ws;                   ws += (size_t)BSD * 4;
  float2* mlbuf = (float2*)ws;                ws += (size_t)M * NH * sizeof(float2);
  (void)wkb; (void)wvb;

  float* out_proj = (float*)d_out;
  float* attnw = (float*)d_out + BSD;

  cvt3_kernel<<<3 * N8_BSD / 256, 256, 0, stream>>>(q_in, k_in, v_in, qbf, ctx1);
  cvt4_kernel<<<4 * N8_DD / 256, 256, 0, stream>>>(wq, wk, wv, wo, wqb);

  gemm_qkv<<<dim3(M / 128, 2304 / 64), 256, 0, stream>>>(qbf, kbf, vbf, wqb,
                                                         Qs, Ks, VT);

  attn_ml<<<32 * NH * BATCH, 256, 0, stream>>>(Qs, Ks, mlbuf);
  attn_p2<<<64 * NH * BATCH, 256, 0, stream>>>(Qs, Ks, VT, mlbuf, attnw,
                                               ctx0, ctx1);
  ctx_reduce<<<BSD / 4 / 256, 256, 0, stream>>>(ctx0, ctx1, ctx);

  gemm_proj<<<dim3(M / 128, DMODEL / 64), 256, 0, stream>>>(ctx, wob, out_proj);
}

// Round 7
// 270.095 us; speedup vs baseline: 1.4053x; 1.0065x over previous
//
#include <hip/hip_runtime.h>

#define BATCH 2
#define S_LEN 2048
#define NH 12
#define DMODEL 768
// DK = 64, scale = 1/8

#define N8_BSD (BATCH * S_LEN * DMODEL / 8)  // 393216
#define N8_DD (DMODEL * DMODEL / 8)          // 73728

typedef __attribute__((ext_vector_type(8))) short bf16x8;
typedef __attribute__((ext_vector_type(4))) float f32x4;
typedef __attribute__((ext_vector_type(4))) unsigned short us4;

__device__ __forceinline__ unsigned short f2bf(float f) {
  union { float f; unsigned int u; } v; v.f = f;
  unsigned int r = v.u + 0x7fffu + ((v.u >> 16) & 1u);  // RNE
  return (unsigned short)(r >> 16);
}

// ------- f32 -> bf16 converts (8 elems/thread); cvt3 also zeroes ctx1 -------
__global__ void cvt3_kernel(const float* __restrict__ s0,
                            const float* __restrict__ s1,
                            const float* __restrict__ s2,
                            unsigned short* __restrict__ dst,
                            float* __restrict__ ctx1) {
  int i = blockIdx.x * blockDim.x + threadIdx.x;  // 0 .. 3*N8_BSD-1 (exact)
  int j = i / N8_BSD;
  int k = i - j * N8_BSD;
  const float* s = (j == 0) ? s0 : (j == 1) ? s1 : s2;
  const float4* sp = (const float4*)s;
  float4 a = sp[k * 2], b = sp[k * 2 + 1];
  us4 o0 = { f2bf(a.x), f2bf(a.y), f2bf(a.z), f2bf(a.w) };
  us4 o1 = { f2bf(b.x), f2bf(b.y), f2bf(b.z), f2bf(b.w) };
  us4* d = (us4*)dst;
  d[i * 2] = o0;
  d[i * 2 + 1] = o1;
  if (j == 0) {  // zero ctx1 partial buffer (BSD f32 = exactly this segment)
    f32x4 z = (f32x4){0.f, 0.f, 0.f, 0.f};
    f32x4* c = (f32x4*)ctx1;
    c[k * 2] = z;
    c[k * 2 + 1] = z;
  }
}

__global__ void cvt4_kernel(const float* __restrict__ s0,
                            const float* __restrict__ s1,
                            const float* __restrict__ s2,
                            const float* __restrict__ s3,
                            unsigned short* __restrict__ dst) {
  int i = blockIdx.x * blockDim.x + threadIdx.x;  // 0 .. 4*N8_DD-1 (exact)
  int j = i / N8_DD;
  int k = i - j * N8_DD;
  const float* s = (j == 0) ? s0 : (j == 1) ? s1 : (j == 2) ? s2 : s3;
  const float4* sp = (const float4*)s;
  float4 a = sp[k * 2], b = sp[k * 2 + 1];
  us4 o0 = { f2bf(a.x), f2bf(a.y), f2bf(a.z), f2bf(a.w) };
  us4 o1 = { f2bf(b.x), f2bf(b.y), f2bf(b.z), f2bf(b.w) };
  us4* d = (us4*)dst;
  d[i * 2] = o0;
  d[i * 2 + 1] = o1;
}

// ------- reduce: ctx_bf16 = f2bf(ctx0 + ctx1), 4 elems/thread -------
__global__ void ctx_reduce(const float* __restrict__ c0,
                           const float* __restrict__ c1,
                           unsigned short* __restrict__ o) {
  int i = blockIdx.x * blockDim.x + threadIdx.x;  // 0 .. BSD/4-1
  float4 a = ((const float4*)c0)[i];
  float4 b = ((const float4*)c1)[i];
  us4 r = { f2bf(a.x + b.x), f2bf(a.y + b.y), f2bf(a.z + b.z), f2bf(a.w + b.w) };
  ((us4*)o)[i] = r;
}

#define GLD_LDS16(g, l)                                                    \
  __builtin_amdgcn_global_load_lds(                                        \
      (const __attribute__((address_space(1))) unsigned int*)(g),          \
      (__attribute__((address_space(3))) unsigned int*)(l), 16, 0, 0)

// ---------------- fused QKV projection GEMM, 128x128 tile ----------------
// grid (32, 18): n0g = blockIdx.y*128 selects Q (0..767), K (768..1535),
// V (1536..2303). W3 = [2304][768] contiguous. BK=64, 4 waves 2x2, acc 4x4.
__global__ __launch_bounds__(256, 2)
void gemm_qkv(const unsigned short* __restrict__ Aq,
              const unsigned short* __restrict__ Ak,
              const unsigned short* __restrict__ Av,
              const unsigned short* __restrict__ W3,
              unsigned short* __restrict__ Qs,
              unsigned short* __restrict__ Ks,
              unsigned short* __restrict__ VT) {
  __shared__ unsigned short As[128 * 64];
  __shared__ unsigned short Bs[128 * 64];
  const int m0 = blockIdx.x * 128;
  const int n0g = blockIdx.y * 128;
  const int nblk = n0g / 768;         // 0=Q 1=K 2=V (uniform per block)
  const int n0 = n0g - nblk * 768;
  const unsigned short* A = (nblk == 0) ? Aq : (nblk == 1) ? Ak : Av;
  const unsigned short* Bw = W3 + (size_t)n0g * DMODEL;
  const int tid = threadIdx.x, w = tid >> 6, l = tid & 63;
  const int lg = l >> 4, ll = l & 15;
  const int wm = w >> 1, wn = w & 1;
  const int lr = l >> 3, lc = (l & 7) * 8;

  f32x4 acc[4][4];
#pragma unroll
  for (int i = 0; i < 4; ++i)
#pragma unroll
    for (int j = 0; j < 4; ++j) acc[i][j] = (f32x4){0.f, 0.f, 0.f, 0.f};

  for (int k0 = 0; k0 < DMODEL; k0 += 64) {
#pragma unroll
    for (int i = 0; i < 4; ++i) {
      GLD_LDS16(A + (size_t)(m0 + w * 32 + i * 8 + lr) * DMODEL + k0 + lc,
                &As[(w * 32 + i * 8) * 64]);
      GLD_LDS16(Bw + (size_t)(w * 32 + i * 8 + lr) * DMODEL + k0 + lc,
                &Bs[(w * 32 + i * 8) * 64]);
    }
    __syncthreads();
#pragma unroll
    for (int t = 0; t < 2; ++t) {
      bf16x8 af[4], bf[4];
#pragma unroll
      for (int mi = 0; mi < 4; ++mi)
        af[mi] = *(const bf16x8*)&As[(wm * 64 + mi * 16 + ll) * 64 + t * 32 + lg * 8];
#pragma unroll
      for (int ni = 0; ni < 4; ++ni)
        bf[ni] = *(const bf16x8*)&Bs[(wn * 64 + ni * 16 + ll) * 64 + t * 32 + lg * 8];
#pragma unroll
      for (int mi = 0; mi < 4; ++mi)
#pragma unroll
        for (int ni = 0; ni < 4; ++ni)
          acc[mi][ni] = __builtin_amdgcn_mfma_f32_16x16x32_bf16(
              af[mi], bf[ni], acc[mi][ni], 0, 0, 0);
    }
    __syncthreads();
  }

  if (nblk < 2) {  // Q or K: row-major [4096][768]; Q scaled by 1/8
    unsigned short* o = nblk ? Ks : Qs;
    const float sc = nblk ? 1.f : 0.125f;
#pragma unroll
    for (int mi = 0; mi < 4; ++mi)
#pragma unroll
      for (int ni = 0; ni < 4; ++ni) {
        const int col = n0 + wn * 64 + ni * 16 + ll;
        const int rowb = m0 + wm * 64 + mi * 16 + lg * 4;
#pragma unroll
        for (int r = 0; r < 4; ++r)
          o[(size_t)(rowb + r) * 768 + col] = f2bf(acc[mi][ni][r] * sc);
      }
  } else {  // V^T: (B,H,64,S)
#pragma unroll
    for (int mi = 0; mi < 4; ++mi)
#pragma unroll
      for (int ni = 0; ni < 4; ++ni) {
        const int col = n0 + wn * 64 + ni * 16 + ll;
        const int row = m0 + wm * 64 + mi * 16 + lg * 4;
        const int bb = row >> 11, sidx = row & (S_LEN - 1);
        const size_t base =
            ((size_t)(bb * NH + (col >> 6)) * 64 + (col & 63)) * S_LEN + sidx;
        us4 pk = { f2bf(acc[mi][ni][0]), f2bf(acc[mi][ni][1]),
                   f2bf(acc[mi][ni][2]), f2bf(acc[mi][ni][3]) };
        *(us4*)&VT[base] = pk;
      }
  }
}

// ---------------- output projection GEMM (f32 out), 128x128 tile ----------
__global__ __launch_bounds__(256, 2)
void gemm_proj(const unsigned short* __restrict__ A,
               const unsigned short* __restrict__ Bw,
               float* __restrict__ o) {
  __shared__ unsigned short As[128 * 64];
  __shared__ unsigned short Bs[128 * 64];
  const int m0 = blockIdx.x * 128, n0 = blockIdx.y * 128;
  const int tid = threadIdx.x, w = tid >> 6, l = tid & 63;
  const int lg = l >> 4, ll = l & 15;
  const int wm = w >> 1, wn = w & 1;
  const int lr = l >> 3, lc = (l & 7) * 8;

  f32x4 acc[4][4];
#pragma unroll
  for (int i = 0; i < 4; ++i)
#pragma unroll
    for (int j = 0; j < 4; ++j) acc[i][j] = (f32x4){0.f, 0.f, 0.f, 0.f};

  for (int k0 = 0; k0 < DMODEL; k0 += 64) {
#pragma unroll
    for (int i = 0; i < 4; ++i) {
      GLD_LDS16(A + (size_t)(m0 + w * 32 + i * 8 + lr) * DMODEL + k0 + lc,
                &As[(w * 32 + i * 8) * 64]);
      GLD_LDS16(Bw + (size_t)(n0 + w * 32 + i * 8 + lr) * DMODEL + k0 + lc,
                &Bs[(w * 32 + i * 8) * 64]);
    }
    __syncthreads();
#pragma unroll
    for (int t = 0; t < 2; ++t) {
      bf16x8 af[4], bf[4];
#pragma unroll
      for (int mi = 0; mi < 4; ++mi)
        af[mi] = *(const bf16x8*)&As[(wm * 64 + mi * 16 + ll) * 64 + t * 32 + lg * 8];
#pragma unroll
      for (int ni = 0; ni < 4; ++ni)
        bf[ni] = *(const bf16x8*)&Bs[(wn * 64 + ni * 16 + ll) * 64 + t * 32 + lg * 8];
#pragma unroll
      for (int mi = 0; mi < 4; ++mi)
#pragma unroll
        for (int ni = 0; ni < 4; ++ni)
          acc[mi][ni] = __builtin_amdgcn_mfma_f32_16x16x32_bf16(
              af[mi], bf[ni], acc[mi][ni], 0, 0, 0);
    }
    __syncthreads();
  }

#pragma unroll
  for (int mi = 0; mi < 4; ++mi)
#pragma unroll
    for (int ni = 0; ni < 4; ++ni) {
      const int col = n0 + wn * 64 + ni * 16 + ll;
      const int rowb = m0 + wm * 64 + mi * 16 + lg * 4;
#pragma unroll
      for (int r = 0; r < 4; ++r)
        o[(size_t)(rowb + r) * DMODEL + col] = acc[mi][ni][r];
    }
}

// ---------------- attn pass 1: online (m, 1/l) only ----------------
__global__ __launch_bounds__(256, 3)
void attn_ml(const unsigned short* __restrict__ Qp,
             const unsigned short* __restrict__ Kp,
             float2* __restrict__ mlbuf) {
  const int idx = blockIdx.x;
  const int qt = 31 - idx / (NH * BATCH);  // heavy tiles first
  const int hb = idx % (NH * BATCH);
  const int h = hb >> 1, b = hb & 1;
  const int tid = threadIdx.x, w = tid >> 6, l = tid & 63;
  const int lg = l >> 4, ll = l & 15;

  const unsigned short* kbp = Kp + (size_t)b * S_LEN * DMODEL + h * 64;
  const int q0 = qt * 64 + w * 16;
  const int nkt = qt + 1;

  bf16x8 qf[2];
  {
    const unsigned short* qb =
        Qp + (size_t)(b * S_LEN + q0 + ll) * DMODEL + h * 64 + lg * 8;
    qf[0] = *(const bf16x8*)qb;
    qf[1] = *(const bf16x8*)(qb + 32);
  }
  int rowg[4];
#pragma unroll
  for (int r = 0; r < 4; ++r) rowg[r] = q0 + lg * 4 + r;

  float m[4], lsum[4];
#pragma unroll
  for (int r = 0; r < 4; ++r) { m[r] = -1e30f; lsum[r] = 0.f; }

  auto LOADK = [&](bf16x8* kf, int kt) {
#pragma unroll
    for (int t = 0; t < 2; ++t)
#pragma unroll
      for (int nb = 0; nb < 4; ++nb)
        kf[t * 4 + nb] = *(const bf16x8*)(kbp +
            (size_t)(kt * 64 + nb * 16 + ll) * DMODEL + t * 32 + lg * 8);
  };

  auto P1TILE = [&](const bf16x8* kf, int kt) {
    f32x4 s[4];
#pragma unroll
    for (int nb = 0; nb < 4; ++nb) s[nb] = (f32x4){0.f, 0.f, 0.f, 0.f};
#pragma unroll
    for (int t = 0; t < 2; ++t)
#pragma unroll
      for (int nb = 0; nb < 4; ++nb)
        s[nb] = __builtin_amdgcn_mfma_f32_16x16x32_bf16(qf[t], kf[t * 4 + nb],
                                                        s[nb], 0, 0, 0);
    if (kt == nkt - 1) {  // diagonal: causal mask
#pragma unroll
      for (int nb = 0; nb < 4; ++nb) {
        const int col = kt * 64 + nb * 16 + ll;
#pragma unroll
        for (int r = 0; r < 4; ++r)
          if (col > rowg[r]) s[nb][r] = -1e30f;
      }
    }
#pragma unroll
    for (int r = 0; r < 4; ++r) {
      float tm = fmaxf(fmaxf(s[0][r], s[1][r]), fmaxf(s[2][r], s[3][r]));
      float mn = fmaxf(m[r], tm);
      float te = __expf(s[0][r] - mn) + __expf(s[1][r] - mn) +
                 __expf(s[2][r] - mn) + __expf(s[3][r] - mn);
      lsum[r] = lsum[r] * __expf(m[r] - mn) + te;
      m[r] = mn;
    }
  };

  {
    bf16x8 ka[8], kb2[8];
    LOADK(ka, 0);
    for (int kt = 0; kt < nkt; kt += 2) {
      if (kt + 1 < nkt) LOADK(kb2, kt + 1);
      P1TILE(ka, kt);
      if (kt + 1 >= nkt) break;
      if (kt + 2 < nkt) LOADK(ka, kt + 2);
      P1TILE(kb2, kt + 1);
    }
  }

  // butterfly combine across the 16 lanes sharing each row
#pragma unroll
  for (int off = 1; off < 16; off <<= 1)
#pragma unroll
    for (int r = 0; r < 4; ++r) {
      float om = __shfl_xor(m[r], off, 64);
      float ol = __shfl_xor(lsum[r], off, 64);
      float mn = fmaxf(m[r], om);
      lsum[r] = lsum[r] * __expf(m[r] - mn) + ol * __expf(om - mn);
      m[r] = mn;
    }

  if (ll == 0) {
    float2* mlb = mlbuf + (size_t)(b * NH + h) * S_LEN;
#pragma unroll
    for (int r = 0; r < 4; ++r)
      mlb[rowg[r]] = make_float2(m[r], 1.f / lsum[r]);
  }
}

// ---------------- attn pass 2: chunked P write + PV ----------------
// Grid: 64 slots x 24 (h,b). Each slot = (chunk of 16 k-tiles, q-tile).
// Single f32 LDS staging tile per wave (16KB/WG): exp writes once; PV bf16
// A-frags built by reading it back + in-register cvt; P stores read it as
// full-line f32x4. Nontemporal P stores keep K/V resident in L2.
__global__ __launch_bounds__(256, 3)
void attn_p2(const unsigned short* __restrict__ Qp,
             const unsigned short* __restrict__ Kp,
             const unsigned short* __restrict__ VTp,
             const float2* __restrict__ mlbuf,
             float* __restrict__ attnw,
             float* __restrict__ ctx0,
             float* __restrict__ ctx1) {
  const int idx = blockIdx.x;
  const int slot = idx / (NH * BATCH);
  const int hb = idx % (NH * BATCH);
  const int h = hb >> 1, b = hb & 1;
  // slot -> (chunk, qt), sorted by value-tile count desc
  int qt, ck;
  if (slot <= 16)      { ck = 0; qt = 15 + slot; }
  else if (slot == 17) { ck = 1; qt = 31; }
  else if (slot < 48)  { int u = slot - 18; int k = 15 - (u >> 1);
                         if (u & 1) { ck = 1; qt = k + 15; } else { ck = 0; qt = k - 1; } }
  else                 { ck = 1; qt = slot - 48; }

  const int ktlo = ck * 16;
  const int kthi = (qt < ktlo + 15) ? qt : (ktlo + 15);  // last value tile
  const bool hasval = (ktlo <= qt);

  const int tid = threadIdx.x, w = tid >> 6, l = tid & 63;
  const int lg = l >> 4, ll = l & 15;
  __shared__ float pf32[4][1024];  // 16x64 f32 per wave (private)
  float* pfw = &pf32[w][0];

  const unsigned short* kbp = Kp + (size_t)b * S_LEN * DMODEL + h * 64;
  const unsigned short* vbp = VTp + ((size_t)(b * NH + h)) * 64 * S_LEN;
  float* pbase = attnw + ((size_t)(b * NH + h)) * S_LEN * S_LEN;

  const int q0 = qt * 64 + w * 16;
  int rowg[4];
#pragma unroll
  for (int r = 0; r < 4; ++r) rowg[r] = q0 + lg * 4 + r;

  if (hasval) {
    bf16x8 qf[2];
    {
      const unsigned short* qb =
          Qp + (size_t)(b * S_LEN + q0 + ll) * DMODEL + h * 64 + lg * 8;
      qf[0] = *(const bf16x8*)qb;
      qf[1] = *(const bf16x8*)(qb + 32);
    }
    float m[4], linv[4];
    {
      const float2* mlb = mlbuf + (size_t)(b * NH + h) * S_LEN;
#pragma unroll
      for (int r = 0; r < 4; ++r) {
        float2 t = mlb[rowg[r]];
        m[r] = t.x;
        linv[r] = t.y;
      }
    }

    f32x4 cacc[4];
#pragma unroll
    for (int nb = 0; nb < 4; ++nb) cacc[nb] = (f32x4){0.f, 0.f, 0.f, 0.f};

    bf16x8 kf[8], vf[8];
#pragma unroll
    for (int t = 0; t < 2; ++t)
#pragma unroll
      for (int nb = 0; nb < 4; ++nb) {
        kf[t * 4 + nb] = *(const bf16x8*)(kbp +
            (size_t)(ktlo * 64 + nb * 16 + ll) * DMODEL + t * 32 + lg * 8);
        vf[t * 4 + nb] = *(const bf16x8*)(vbp +
            (size_t)(nb * 16 + ll) * S_LEN + ktlo * 64 + t * 32 + lg * 8);
      }

    for (int kt = ktlo; kt <= kthi; ++kt) {
      // QK^T
      f32x4 s[4];
#pragma unroll
      for (int nb = 0; nb < 4; ++nb) s[nb] = (f32x4){0.f, 0.f, 0.f, 0.f};
#pragma unroll
      for (int t = 0; t < 2; ++t)
#pragma unroll
        for (int nb = 0; nb < 4; ++nb)
          s[nb] = __builtin_amdgcn_mfma_f32_16x16x32_bf16(qf[t], kf[t * 4 + nb],
                                                          s[nb], 0, 0, 0);
      // p (masked -> exact 0) -> f32 LDS (swz: col ^ ((row>>2)&1)<<4)
#pragma unroll
      for (int nb = 0; nb < 4; ++nb) {
        const int col = kt * 64 + nb * 16 + ll;
#pragma unroll
        for (int r = 0; r < 4; ++r) {
          float p = (col <= rowg[r]) ? __expf(s[nb][r] - m[r]) * linv[r] : 0.f;
          const int rl = lg * 4 + r;
          pfw[rl * 64 + ((nb * 16 + ll) ^ ((lg & 1) << 4))] = p;
        }
      }
      // PV A-frags: read f32 tile (row=ll, cols t*32+lg*8..+8) + cvt to bf16
      bf16x8 pf[2];
#pragma unroll
      for (int t = 0; t < 2; ++t) {
        const int c0 = (t * 32 + lg * 8) ^ (((ll >> 2) & 1) << 4);
        f32x4 lo = *(const f32x4*)&pfw[ll * 64 + c0];
        f32x4 hi = *(const f32x4*)&pfw[ll * 64 + c0 + 4];
        union { us4 h[2]; bf16x8 v; } u;
        u.h[0] = (us4){ f2bf(lo[0]), f2bf(lo[1]), f2bf(lo[2]), f2bf(lo[3]) };
        u.h[1] = (us4){ f2bf(hi[0]), f2bf(hi[1]), f2bf(hi[2]), f2bf(hi[3]) };
        pf[t] = u.v;
      }
      // PV (uses current vf)
#pragma unroll
      for (int t = 0; t < 2; ++t)
#pragma unroll
        for (int nb = 0; nb < 4; ++nb)
          cacc[nb] = __builtin_amdgcn_mfma_f32_16x16x32_bf16(
              pf[t], vf[t * 4 + nb], cacc[nb], 0, 0, 0);
      // issue next tile's loads BEFORE this tile's stores (FIFO decoupling)
      if (kt < kthi) {
#pragma unroll
        for (int t = 0; t < 2; ++t)
#pragma unroll
          for (int nb = 0; nb < 4; ++nb) {
            kf[t * 4 + nb] = *(const bf16x8*)(kbp +
                (size_t)((kt + 1) * 64 + nb * 16 + ll) * DMODEL + t * 32 + lg * 8);
            vf[t * 4 + nb] = *(const bf16x8*)(vbp +
                (size_t)(nb * 16 + ll) * S_LEN + (kt + 1) * 64 + t * 32 + lg * 8);
          }
      }
      // coalesced nontemporal P stores: 4 rows x 256B full lines per pass
#pragma unroll
      for (int ps = 0; ps < 4; ++ps) {
        const int row = ps * 4 + lg;                       // (row>>2)&1 == ps&1
        const int cb = (ll * 4) ^ ((ps & 1) << 4);
        f32x4 pv = *(const f32x4*)&pfw[row * 64 + cb];
        __builtin_nontemporal_store(
            pv, (f32x4*)&pbase[(size_t)(q0 + row) * S_LEN + kt * 64 + ll * 4]);
      }
    }

    // PV partial -> ctx0/ctx1, coalesced via same f32 LDS tile
#pragma unroll
    for (int nb = 0; nb < 4; ++nb)
#pragma unroll
      for (int r = 0; r < 4; ++r) {
        const int rl = lg * 4 + r;
        pfw[rl * 64 + ((nb * 16 + ll) ^ ((lg & 1) << 4))] = cacc[nb][r];
      }
    float* co = ck ? ctx1 : ctx0;
#pragma unroll
    for (int ps = 0; ps < 4; ++ps) {
      const int row = ps * 4 + lg;
      const int cb = (ll * 4) ^ ((ps & 1) << 4);
      f32x4 cv = *(const f32x4*)&pfw[row * 64 + cb];
      *(f32x4*)&co[(size_t)(b * S_LEN + q0 + row) * DMODEL + h * 64 + ll * 4] = cv;
    }
  }

  // zero-fill masked columns inside this chunk (overwrite 0xAA poison)
  const int zs = ((qt + 1) * 64 > ktlo * 64) ? (qt + 1) * 64 : ktlo * 64;
  const int ze = (ktlo + 16) * 64;
  if (zs < ze) {
    f32x4 z = (f32x4){0.f, 0.f, 0.f, 0.f};
    for (int rr = 0; rr < 16; ++rr) {
      float* dst = pbase + (size_t)(q0 + rr) * S_LEN;
      for (int c = zs + l * 4; c < ze; c += 256)
        __builtin_nontemporal_store(z, (f32x4*)(dst + c));
    }
  }
}

extern "C" void kernel_launch(void* const* d_in, const int* in_sizes, int n_in,
                              void* d_out, int out_size, void* d_ws, size_t ws_size,
                              hipStream_t stream) {
  const float* q_in = (const float*)d_in[0];
  const float* k_in = (const float*)d_in[1];
  const float* v_in = (const float*)d_in[2];
  // d_in[3] = mask: causal triu(k=1), hardcoded in attn kernels
  const float* wq = (const float*)d_in[4];
  const float* wk = (const float*)d_in[5];
  const float* wv = (const float*)d_in[6];
  const float* wo = (const float*)d_in[7];

  const int BSD = BATCH * S_LEN * DMODEL;  // 3145728
  const int DD = DMODEL * DMODEL;          // 589824
  const int M = BATCH * S_LEN;             // 4096

  char* ws = (char*)d_ws;
  unsigned short* qbf = (unsigned short*)ws;  ws += (size_t)BSD * 2;
  unsigned short* kbf = (unsigned short*)ws;  ws += (size_t)BSD * 2;
  unsigned short* vbf = (unsigned short*)ws;  ws += (size_t)BSD * 2;
  unsigned short* wqb = (unsigned short*)ws;  ws += (size_t)DD * 2;   // contiguous
  unsigned short* wkb = (unsigned short*)ws;  ws += (size_t)DD * 2;   //  W3 =
  unsigned short* wvb = (unsigned short*)ws;  ws += (size_t)DD * 2;   //  [2304][768]
  unsigned short* wob = (unsigned short*)ws;  ws += (size_t)DD * 2;
  unsigned short* Qs  = (unsigned short*)ws;  ws += (size_t)BSD * 2;
  unsigned short* Ks  = (unsigned short*)ws;  ws += (size_t)BSD * 2;
  unsigned short* VT  = (unsigned short*)ws;  ws += (size_t)BSD * 2;
  unsigned short* ctx = (unsigned short*)ws;  ws += (size_t)BSD * 2;
  float* ctx0 = (float*)ws;                   ws += (size_t)BSD * 4;
  float* ctx1 = (float*)ws;                   ws += (size_t)BSD * 4;
  float2* mlbuf = (float2*)ws;                ws += (size_t)M * NH * sizeof(float2);
  (void)wkb; (void)wvb;

  float* out_proj = (float*)d_out;
  float* attnw = (float*)d_out + BSD;

  cvt3_kernel<<<3 * N8_BSD / 256, 256, 0, stream>>>(q_in, k_in, v_in, qbf, ctx1);
  cvt4_kernel<<<4 * N8_DD / 256, 256, 0, stream>>>(wq, wk, wv, wo, wqb);

  gemm_qkv<<<dim3(M / 128, 2304 / 128), 256, 0, stream>>>(qbf, kbf, vbf, wqb,
                                                          Qs, Ks, VT);

  attn_ml<<<32 * NH * BATCH, 256, 0, stream>>>(Qs, Ks, mlbuf);
  attn_p2<<<64 * NH * BATCH, 256, 0, stream>>>(Qs, Ks, VT, mlbuf, attnw,
                                               ctx0, ctx1);
  ctx_reduce<<<BSD / 4 / 256, 256, 0, stream>>>(ctx0, ctx1, ctx);

  gemm_proj<<<dim3(M / 128, DMODEL / 128), 256, 0, stream>>>(ctx, wob, out_proj);
}